// Round 15
// baseline (240.875 us; speedup 1.0000x reference)
//
#include <hip/hip_runtime.h>
#include <math.h>

#define NN 4096
#define DM 128
#define NE 131072
#define QSCALE 0.36067376022224085f   // 0.25 * log2(e): exp(S/4) == exp2(S_prescaled)
#define ESCALE 0.36067376022224085f

typedef short short8 __attribute__((ext_vector_type(8)));
typedef float f32x4  __attribute__((ext_vector_type(4)));
typedef unsigned int uint4v __attribute__((ext_vector_type(4)));

// round-half-up pack of two fp32 -> bf16x2 via v_perm_b32
static __device__ __forceinline__ unsigned pk2(float lo, float hi) {
  union { float f; unsigned u; } a, b; a.f = lo; b.f = hi;
  return __builtin_amdgcn_perm(b.u + 0x8000u, a.u + 0x8000u, 0x07060302u);
}
// truncating pack via v_perm_b32 (1 op)
static __device__ __forceinline__ unsigned pkp(float lo, float hi) {
  union { float f; unsigned u; } a, b; a.f = lo; b.f = hi;
  return __builtin_amdgcn_perm(b.u, a.u, 0x07060302u);
}
static __device__ __forceinline__ unsigned short f2bh(float f) {
  union { float f; unsigned u; } v; v.f = f;
  return (unsigned short)((v.u + 0x8000u) >> 16);
}
static __device__ __forceinline__ float b2f16(unsigned short u) {
  union { unsigned u; float f; } v; v.u = ((unsigned)u) << 16; return v.f;
}
static __device__ __forceinline__ short8 cvt8(float4 a, float4 b) {
  uint4v u;
  u.x = pk2(a.x, a.y); u.y = pk2(a.z, a.w);
  u.z = pk2(b.x, b.y); u.w = pk2(b.z, b.w);
  return __builtin_bit_cast(short8, u);
}
static __device__ __forceinline__ int detect64(const int* __restrict__ EI) {
  int v = EI[2 * (threadIdx.x & 63) + 1];
  for (int off = 1; off < 64; off <<= 1) v |= __shfl_xor(v, off);
  return (v == 0) ? 1 : 0;
}

__global__ __launch_bounds__(256) void k_fill(float* __restrict__ out, float v, int n) {
  int i = blockIdx.x * 256 + threadIdx.x;
  if (i < n) out[i] = v;
}

// ---------------- MFMA GEMM: C = epi(A @ W^T + Bias) * oscale ----------------
__global__ __launch_bounds__(256) void gemm_mfma(
    const float* __restrict__ A0, int lda0,
    const float* __restrict__ A1, int lda1, int ksplit,
    const float* __restrict__ Wt, const float* __restrict__ Bias,
    const float* __restrict__ Res, const float* __restrict__ E0, const float* __restrict__ E1,
    void* __restrict__ Cp, int Nt, int K, int act, int omode, float oscale)
{
  __shared__ short Asm[64][40];
  __shared__ short Wsm[64][40];
  const int m0 = blockIdx.x * 64, n0 = blockIdx.y * 64;
  const int tid = threadIdx.x;
  const int srow = tid >> 2, koff = (tid & 3) * 8;
  const int lane = tid & 63, wave = tid >> 6;
  const int quad = lane >> 4, m16 = lane & 15;
  f32x4 acc[4];
#pragma unroll
  for (int i = 0; i < 4; i++) acc[i] = {0.f, 0.f, 0.f, 0.f};

  for (int k0 = 0; k0 < K; k0 += 32) {
    const int kg = k0 + koff;
    const float* ap = (kg < ksplit) ? (A0 + (size_t)(m0 + srow) * lda0 + kg)
                                    : (A1 + (size_t)(m0 + srow) * lda1 + (kg - ksplit));
    float4 a0 = *(const float4*)ap, a1 = *(const float4*)(ap + 4);
    const float* wp = Wt + (size_t)(n0 + srow) * K + kg;
    float4 w0 = *(const float4*)wp, w1v = *(const float4*)(wp + 4);
    __syncthreads();
    *(short8*)&Asm[srow][koff] = cvt8(a0, a1);
    *(short8*)&Wsm[srow][koff] = cvt8(w0, w1v);
    __syncthreads();
    short8 af = *(short8*)&Asm[wave * 16 + m16][quad * 8];
#pragma unroll
    for (int nt = 0; nt < 4; nt++) {
      short8 bf = *(short8*)&Wsm[nt * 16 + m16][quad * 8];
      acc[nt] = __builtin_amdgcn_mfma_f32_16x16x32_bf16(af, bf, acc[nt], 0, 0, 0);
    }
  }
#pragma unroll
  for (int nt = 0; nt < 4; nt++) {
#pragma unroll
    for (int r = 0; r < 4; r++) {
      const int m = m0 + wave * 16 + quad * 4 + r;
      const int n = n0 + nt * 16 + m16;
      float v = acc[nt][r] + Bias[n];
      size_t oi = (size_t)m * Nt + n;
      if (act == 1) v = 0.5f * v * (1.0f + erff(v * 0.70710678118654752f));
      else if (act == 2) {
        float g = 1.0f / (1.0f + __expf(fminf(fmaxf(-v, -80.f), 80.f)));
        v = g * E0[oi] + (1.0f - g) * E1[oi];
      }
      if (Res) v += Res[oi];
      v *= oscale;
      if (omode == 0)      ((float*)Cp)[oi] = v;
      else if (omode == 1) ((unsigned short*)Cp)[oi] = f2bh(v);
      else                 ((unsigned short*)Cp)[(size_t)n * NN + m] = f2bh(v);
    }
  }
}

// ---------------- six-way QKV GEMM with inline LN; block(0,0) zeroes deg ----------------
// omode: 0 fp32 [m][n]; 1 bf16 [m][n]; 2 bf16 [n][NN+m] (V^T); 3 bf16 head-major Kh[8][4096][16]
#define LN1(V, GV, BV) V = (V - mean) * rstd * GV + BV
__global__ __launch_bounds__(256) void gemm_six(
    const float* __restrict__ X,
    const float* __restrict__ G1, const float* __restrict__ Be1,
    const float* __restrict__ W0, const float* __restrict__ W1, const float* __restrict__ W2,
    const float* __restrict__ W3, const float* __restrict__ W4, const float* __restrict__ W5,
    const float* __restrict__ B0, const float* __restrict__ B1, const float* __restrict__ B2,
    const float* __restrict__ B3, const float* __restrict__ B4, const float* __restrict__ B5,
    void* __restrict__ O0, void* __restrict__ O1, void* __restrict__ O2,
    void* __restrict__ O3, void* __restrict__ O4, void* __restrict__ O5,
    int* __restrict__ deg)
{
  __shared__ short Asm[64][40];
  __shared__ short Wsm[64][40];
  if (blockIdx.x == 0 && blockIdx.y == 0) {
#pragma unroll
    for (int i = 0; i < 16; i++) deg[threadIdx.x * 16 + i] = 0;
  }
  const int g = blockIdx.y >> 1;
  const float* Wt  = (g==0)?W0:(g==1)?W1:(g==2)?W2:(g==3)?W3:(g==4)?W4:W5;
  const float* Bia = (g==0)?B0:(g==1)?B1:(g==2)?B2:(g==3)?B3:(g==4)?B4:B5;
  void* Cp         = (g==0)?O0:(g==1)?O1:(g==2)?O2:(g==3)?O3:(g==4)?O4:O5;
  const int omode  = (g==2)?1:(g==3)?1:(g==4)?3:(g==5)?2:0;
  const float osc  = (g==3)? QSCALE : (g==0)? ESCALE : 1.f;
  const int m0 = blockIdx.x * 64, n0 = (blockIdx.y & 1) * 64;
  const int tid = threadIdx.x;
  const int srow = tid >> 2, koff = (tid & 3) * 8;
  const int lane = tid & 63, wave = tid >> 6;
  const int quad = lane >> 4, m16 = lane & 15;

  const float* arow = X + (size_t)(m0 + srow) * 128 + koff;
  float4 a0[4], a1[4];
#pragma unroll
  for (int c = 0; c < 4; c++) {
    a0[c] = *(const float4*)(arow + c * 32);
    a1[c] = *(const float4*)(arow + c * 32 + 4);
  }
  if (g >= 3) {
    float s = 0.f;
#pragma unroll
    for (int c = 0; c < 4; c++)
      s += a0[c].x + a0[c].y + a0[c].z + a0[c].w + a1[c].x + a1[c].y + a1[c].z + a1[c].w;
    s += __shfl_xor(s, 1); s += __shfl_xor(s, 2);
    float mean = s * (1.0f / 128.0f);
    float v = 0.f;
#pragma unroll
    for (int c = 0; c < 4; c++) {
      float d;
      d = a0[c].x - mean; v += d*d;  d = a0[c].y - mean; v += d*d;
      d = a0[c].z - mean; v += d*d;  d = a0[c].w - mean; v += d*d;
      d = a1[c].x - mean; v += d*d;  d = a1[c].y - mean; v += d*d;
      d = a1[c].z - mean; v += d*d;  d = a1[c].w - mean; v += d*d;
    }
    v += __shfl_xor(v, 1); v += __shfl_xor(v, 2);
    float rstd = rsqrtf(v * (1.0f / 128.0f) + 1e-5f);
#pragma unroll
    for (int c = 0; c < 4; c++) {
      const int col = c * 32 + koff;
      float4 gv0 = *(const float4*)(G1 + col),  gv1 = *(const float4*)(G1 + col + 4);
      float4 bv0 = *(const float4*)(Be1 + col), bv1 = *(const float4*)(Be1 + col + 4);
      LN1(a0[c].x, gv0.x, bv0.x); LN1(a0[c].y, gv0.y, bv0.y);
      LN1(a0[c].z, gv0.z, bv0.z); LN1(a0[c].w, gv0.w, bv0.w);
      LN1(a1[c].x, gv1.x, bv1.x); LN1(a1[c].y, gv1.y, bv1.y);
      LN1(a1[c].z, gv1.z, bv1.z); LN1(a1[c].w, gv1.w, bv1.w);
    }
  }

  f32x4 acc[4];
#pragma unroll
  for (int i = 0; i < 4; i++) acc[i] = {0.f, 0.f, 0.f, 0.f};
#pragma unroll
  for (int c = 0; c < 4; c++) {
    const float* wp = Wt + (size_t)(n0 + srow) * 128 + c * 32 + koff;
    float4 w0 = *(const float4*)wp, w1v = *(const float4*)(wp + 4);
    __syncthreads();
    *(short8*)&Asm[srow][koff] = cvt8(a0[c], a1[c]);
    *(short8*)&Wsm[srow][koff] = cvt8(w0, w1v);
    __syncthreads();
    short8 af = *(short8*)&Asm[wave * 16 + m16][quad * 8];
#pragma unroll
    for (int nt = 0; nt < 4; nt++) {
      short8 bf = *(short8*)&Wsm[nt * 16 + m16][quad * 8];
      acc[nt] = __builtin_amdgcn_mfma_f32_16x16x32_bf16(af, bf, acc[nt], 0, 0, 0);
    }
  }
#pragma unroll
  for (int nt = 0; nt < 4; nt++) {
#pragma unroll
    for (int r = 0; r < 4; r++) {
      const int m = m0 + wave * 16 + quad * 4 + r;
      const int n = n0 + nt * 16 + m16;
      float v = (acc[nt][r] + Bia[n]) * osc;
      size_t oi = (size_t)m * 128 + n;
      if (omode == 0)      ((float*)Cp)[oi] = v;
      else if (omode == 1) ((unsigned short*)Cp)[oi] = f2bh(v);
      else if (omode == 3) ((unsigned short*)Cp)[(size_t)(n >> 4) * (NN * 16) + (size_t)m * 16 + (n & 15)] = f2bh(v);
      else                 ((unsigned short*)Cp)[(size_t)n * NN + m] = f2bh(v);
    }
  }
}

// ---------------- dual GEMM: y<2 = gate (K=256, act2), y>=2 = wo (K=128) ----------------
__global__ __launch_bounds__(256) void gemm_dual(
    const float* __restrict__ X, const float* __restrict__ AGG,
    const float* __restrict__ GO,
    const float* __restrict__ Wg, const float* __restrict__ Bg,
    const float* __restrict__ Wo, const float* __restrict__ Bo,
    float* __restrict__ LOCAL, float* __restrict__ GOP)
{
  __shared__ short Asm[64][40];
  __shared__ short Wsm[64][40];
  const int isGate = (blockIdx.y < 2);
  const float* A0  = isGate ? X   : GO;
  const float* A1  = isGate ? AGG : GO;
  const int ksplit = 128;
  const int K      = isGate ? 256 : 128;
  const float* Wt  = isGate ? Wg : Wo;
  const float* Bia = isGate ? Bg : Bo;
  float* Cp        = isGate ? LOCAL : GOP;
  const int m0 = blockIdx.x * 64, n0 = (blockIdx.y & 1) * 64;
  const int tid = threadIdx.x;
  const int srow = tid >> 2, koff = (tid & 3) * 8;
  const int lane = tid & 63, wave = tid >> 6;
  const int quad = lane >> 4, m16 = lane & 15;
  f32x4 acc[4];
#pragma unroll
  for (int i = 0; i < 4; i++) acc[i] = {0.f, 0.f, 0.f, 0.f};

  for (int k0 = 0; k0 < K; k0 += 32) {
    const int kg = k0 + koff;
    const float* ap = (kg < ksplit) ? (A0 + (size_t)(m0 + srow) * 128 + kg)
                                    : (A1 + (size_t)(m0 + srow) * 128 + (kg - ksplit));
    float4 a0 = *(const float4*)ap, a1 = *(const float4*)(ap + 4);
    const float* wp = Wt + (size_t)(n0 + srow) * K + kg;
    float4 w0 = *(const float4*)wp, w1v = *(const float4*)(wp + 4);
    __syncthreads();
    *(short8*)&Asm[srow][koff] = cvt8(a0, a1);
    *(short8*)&Wsm[srow][koff] = cvt8(w0, w1v);
    __syncthreads();
    short8 af = *(short8*)&Asm[wave * 16 + m16][quad * 8];
#pragma unroll
    for (int nt = 0; nt < 4; nt++) {
      short8 bf = *(short8*)&Wsm[nt * 16 + m16][quad * 8];
      acc[nt] = __builtin_amdgcn_mfma_f32_16x16x32_bf16(af, bf, acc[nt], 0, 0, 0);
    }
  }
#pragma unroll
  for (int nt = 0; nt < 4; nt++) {
#pragma unroll
    for (int r = 0; r < 4; r++) {
      const int m = m0 + wave * 16 + quad * 4 + r;
      const int n = n0 + nt * 16 + m16;
      float v = acc[nt][r] + Bia[n];
      size_t oi = (size_t)m * 128 + n;
      if (isGate) {
        float g = 1.0f / (1.0f + __expf(fminf(fmaxf(-v, -80.f), 80.f)));
        v = g * AGG[oi] + (1.0f - g) * X[oi];
      }
      Cp[oi] = v;
    }
  }
}

// ---------------- FUSED: global attention (blocks 0..1023, 32 q-rows) + edge (1024..3071) ----------------
// gattn: 32-row q-tiles x 8-way key split -> 2x parallelism vs R13 (1024 blocks, 17.4KB LDS).
__global__ __launch_bounds__(512) void k_attn_fused(
    const unsigned short* __restrict__ Kh, const unsigned short* __restrict__ Qb,
    const unsigned short* __restrict__ VT, float* __restrict__ O,
    const int* __restrict__ EI, const float* __restrict__ Q, const float* __restrict__ Kl,
    unsigned short* __restrict__ EB, int* __restrict__ deg)
{
  __shared__ float LO[8][2][16][16];
  __shared__ float LL[8][2][16];
  if (blockIdx.x >= 1024) {
    // -------- edge attention part (2048 blocks x 512 thr = NE*8 lanes) --------
    int is64 = detect64(EI);
    int gid = (blockIdx.x - 1024) * 512 + threadIdx.x;
    int e = gid >> 3, hh = gid & 7;
    int s = is64 ? EI[2*e]      : EI[e];
    int d = is64 ? EI[2*(NE+e)] : EI[NE+e];
    s = min(max(s, 0), NN-1); d = min(max(d, 0), NN-1);
    const float4* qp = (const float4*)(Q  + (size_t)d * DM + hh * 16);
    const float4* kp = (const float4*)(Kl + (size_t)s * DM + hh * 16);
    float acc = 0.f;
#pragma unroll
    for (int c = 0; c < 4; c++) {
      float4 qa = qp[c], ka = kp[c];
      acc += qa.x*ka.x + qa.y*ka.y + qa.z*ka.z + qa.w*ka.w;
    }
    EB[(size_t)e*8 + hh] = f2bh(__builtin_amdgcn_exp2f(fminf(acc, 43.0f)));
    if (hh == 0) atomicAdd(&deg[d], 1);
    return;
  }
  // -------- global attention part --------
  const int h = blockIdx.x >> 7, qt = blockIdx.x & 127;
  const int tid = threadIdx.x, lane = tid & 63, wave = tid >> 6;   // wave 0..7
  const int quad = lane >> 4, m16 = lane & 15;
  const int r0 = qt * 32;
  const short8 z8 = {0,0,0,0,0,0,0,0};
  const f32x4  z4 = {0.f,0.f,0.f,0.f};
  short8 qf[2] = {z8, z8};
  if (quad < 2) {
#pragma unroll
    for (int j = 0; j < 2; j++)
      qf[j] = *(const short8*)(Qb + (size_t)(r0 + j * 16 + m16) * DM + h * 16 + quad * 8);
  }
  short8 ones;
#pragma unroll
  for (int i = 0; i < 8; i++) ones[i] = (short)0x3F80;
  const int kperm = (m16 >> 2) * 8 + (m16 & 3);
  const int kbase = wave * 512;
  const unsigned short* khead = Kh + (size_t)h * (NN * 16);
  f32x4 acc[2] = {z4, z4};
  f32x4 acc2[2] = {z4, z4};
  short8 a0 = z8, a1 = z8, a2 = z8, a3 = z8;
  for (int kt = 0; kt < 8; kt++) {
    const int key0 = kbase + kt * 64;
    if (quad < 2) {
      const unsigned short* kp = khead + (size_t)(key0 + kperm) * 16 + quad * 8;
      a0 = *(const short8*)kp;
      a1 = *(const short8*)(kp + 4 * 16);
      a2 = *(const short8*)(kp + 32 * 16);
      a3 = *(const short8*)(kp + 36 * 16);
    }
    const unsigned short* vp = VT + (size_t)(h * 16 + m16) * NN + key0 + quad * 8;
    short8 av0 = *(const short8*)vp;
    short8 av1 = *(const short8*)(vp + 32);
#pragma unroll
    for (int j = 0; j < 2; j++) {
      f32x4 s0 = __builtin_amdgcn_mfma_f32_16x16x32_bf16(a0, qf[j], z4, 0, 0, 0);
      f32x4 s1 = __builtin_amdgcn_mfma_f32_16x16x32_bf16(a1, qf[j], z4, 0, 0, 0);
      f32x4 s2 = __builtin_amdgcn_mfma_f32_16x16x32_bf16(a2, qf[j], z4, 0, 0, 0);
      f32x4 s3 = __builtin_amdgcn_mfma_f32_16x16x32_bf16(a3, qf[j], z4, 0, 0, 0);
      float e0 = __builtin_amdgcn_exp2f(s0[0]), e1 = __builtin_amdgcn_exp2f(s0[1]);
      float e2 = __builtin_amdgcn_exp2f(s0[2]), e3 = __builtin_amdgcn_exp2f(s0[3]);
      float e4 = __builtin_amdgcn_exp2f(s1[0]), e5 = __builtin_amdgcn_exp2f(s1[1]);
      float e6 = __builtin_amdgcn_exp2f(s1[2]), e7 = __builtin_amdgcn_exp2f(s1[3]);
      uint4v u;
      u.x = pkp(e0, e1); u.y = pkp(e2, e3); u.z = pkp(e4, e5); u.w = pkp(e6, e7);
      short8 p0 = __builtin_bit_cast(short8, u);
      float f0 = __builtin_amdgcn_exp2f(s2[0]), f1 = __builtin_amdgcn_exp2f(s2[1]);
      float f2 = __builtin_amdgcn_exp2f(s2[2]), f3 = __builtin_amdgcn_exp2f(s2[3]);
      float f4 = __builtin_amdgcn_exp2f(s3[0]), f5 = __builtin_amdgcn_exp2f(s3[1]);
      float f6 = __builtin_amdgcn_exp2f(s3[2]), f7 = __builtin_amdgcn_exp2f(s3[3]);
      uint4v w;
      w.x = pkp(f0, f1); w.y = pkp(f2, f3); w.z = pkp(f4, f5); w.w = pkp(f6, f7);
      short8 p1 = __builtin_bit_cast(short8, w);
      acc[j]  = __builtin_amdgcn_mfma_f32_16x16x32_bf16(av0, p0, acc[j], 0, 0, 0);
      acc[j]  = __builtin_amdgcn_mfma_f32_16x16x32_bf16(av1, p1, acc[j], 0, 0, 0);
      acc2[j] = __builtin_amdgcn_mfma_f32_16x16x32_bf16(ones, p0, acc2[j], 0, 0, 0);
      acc2[j] = __builtin_amdgcn_mfma_f32_16x16x32_bf16(ones, p1, acc2[j], 0, 0, 0);
    }
  }
#pragma unroll
  for (int j = 0; j < 2; j++) {
    float4 a4; a4.x = acc[j][0]; a4.y = acc[j][1]; a4.z = acc[j][2]; a4.w = acc[j][3];
    *(float4*)&LO[wave][j][m16][quad * 4] = a4;
    if (lane < 16) LL[wave][j][lane] = acc2[j][0];
  }
  __syncthreads();
  if (wave < 2) {
    const int j = wave;
    float4 o = *(float4*)&LO[0][j][m16][quad * 4];
    float lt = LL[0][j][m16];
#pragma unroll
    for (int w2 = 1; w2 < 8; w2++) {
      float4 t = *(float4*)&LO[w2][j][m16][quad * 4];
      o.x += t.x; o.y += t.y; o.z += t.z; o.w += t.w;
      lt += LL[w2][j][m16];
    }
    float inv = 1.0f / fmaxf(lt, 1e-30f);
    float4 r4; r4.x = o.x * inv; r4.y = o.y * inv; r4.z = o.z * inv; r4.w = o.w * inv;
    *(float4*)(O + (size_t)(r0 + j * 16 + m16) * DM + h * 16 + quad * 4) = r4;
  }
}

// ---------------- FFN first GEMM with inline h = x+relu(ln1(T)) and ln2 ----------------
__global__ __launch_bounds__(256) void gemm_ffn1(
    const float* __restrict__ T, const float* __restrict__ X,
    const float* __restrict__ Gf, const float* __restrict__ Bef,
    const float* __restrict__ G2, const float* __restrict__ Be2,
    const float* __restrict__ W1, const float* __restrict__ B1,
    float* __restrict__ H, float* __restrict__ T1)
{
  __shared__ short Asm[64][40];
  __shared__ short Wsm[64][40];
  const int m0 = blockIdx.x * 64, n0 = blockIdx.y * 64;
  const int tid = threadIdx.x;
  const int srow = tid >> 2, koff = (tid & 3) * 8;
  const int lane = tid & 63, wave = tid >> 6;
  const int quad = lane >> 4, m16 = lane & 15;

  const float* trow = T + (size_t)(m0 + srow) * 128 + koff;
  const float* xrow = X + (size_t)(m0 + srow) * 128 + koff;
  float4 a0[4], a1[4];
#pragma unroll
  for (int c = 0; c < 4; c++) {
    a0[c] = *(const float4*)(trow + c * 32);
    a1[c] = *(const float4*)(trow + c * 32 + 4);
  }
  {
    float s = 0.f;
#pragma unroll
    for (int c = 0; c < 4; c++)
      s += a0[c].x + a0[c].y + a0[c].z + a0[c].w + a1[c].x + a1[c].y + a1[c].z + a1[c].w;
    s += __shfl_xor(s, 1); s += __shfl_xor(s, 2);
    float mean = s * (1.0f / 128.0f);
    float v = 0.f;
#pragma unroll
    for (int c = 0; c < 4; c++) {
      float d;
      d = a0[c].x - mean; v += d*d;  d = a0[c].y - mean; v += d*d;
      d = a0[c].z - mean; v += d*d;  d = a0[c].w - mean; v += d*d;
      d = a1[c].x - mean; v += d*d;  d = a1[c].y - mean; v += d*d;
      d = a1[c].z - mean; v += d*d;  d = a1[c].w - mean; v += d*d;
    }
    v += __shfl_xor(v, 1); v += __shfl_xor(v, 2);
    float rstd = rsqrtf(v * (1.0f / 128.0f) + 1e-5f);
#pragma unroll
    for (int c = 0; c < 4; c++) {
      const int col = c * 32 + koff;
      float4 gv0 = *(const float4*)(Gf + col),  gv1 = *(const float4*)(Gf + col + 4);
      float4 bv0 = *(const float4*)(Bef + col), bv1 = *(const float4*)(Bef + col + 4);
      float4 x0 = *(const float4*)(xrow + c * 32), x1 = *(const float4*)(xrow + c * 32 + 4);
      LN1(a0[c].x, gv0.x, bv0.x); LN1(a0[c].y, gv0.y, bv0.y);
      LN1(a0[c].z, gv0.z, bv0.z); LN1(a0[c].w, gv0.w, bv0.w);
      LN1(a1[c].x, gv1.x, bv1.x); LN1(a1[c].y, gv1.y, bv1.y);
      LN1(a1[c].z, gv1.z, bv1.z); LN1(a1[c].w, gv1.w, bv1.w);
      a0[c].x = x0.x + fmaxf(a0[c].x, 0.f); a0[c].y = x0.y + fmaxf(a0[c].y, 0.f);
      a0[c].z = x0.z + fmaxf(a0[c].z, 0.f); a0[c].w = x0.w + fmaxf(a0[c].w, 0.f);
      a1[c].x = x1.x + fmaxf(a1[c].x, 0.f); a1[c].y = x1.y + fmaxf(a1[c].y, 0.f);
      a1[c].z = x1.z + fmaxf(a1[c].z, 0.f); a1[c].w = x1.w + fmaxf(a1[c].w, 0.f);
      if (blockIdx.y == 0) {
        *(float4*)(H + (size_t)(m0 + srow) * 128 + c * 32 + koff)     = a0[c];
        *(float4*)(H + (size_t)(m0 + srow) * 128 + c * 32 + koff + 4) = a1[c];
      }
    }
  }
  {
    float s = 0.f;
#pragma unroll
    for (int c = 0; c < 4; c++)
      s += a0[c].x + a0[c].y + a0[c].z + a0[c].w + a1[c].x + a1[c].y + a1[c].z + a1[c].w;
    s += __shfl_xor(s, 1); s += __shfl_xor(s, 2);
    float mean = s * (1.0f / 128.0f);
    float v = 0.f;
#pragma unroll
    for (int c = 0; c < 4; c++) {
      float d;
      d = a0[c].x - mean; v += d*d;  d = a0[c].y - mean; v += d*d;
      d = a0[c].z - mean; v += d*d;  d = a0[c].w - mean; v += d*d;
      d = a1[c].x - mean; v += d*d;  d = a1[c].y - mean; v += d*d;
      d = a1[c].z - mean; v += d*d;  d = a1[c].w - mean; v += d*d;
    }
    v += __shfl_xor(v, 1); v += __shfl_xor(v, 2);
    float rstd = rsqrtf(v * (1.0f / 128.0f) + 1e-5f);
#pragma unroll
    for (int c = 0; c < 4; c++) {
      const int col = c * 32 + koff;
      float4 gv0 = *(const float4*)(G2 + col),  gv1 = *(const float4*)(G2 + col + 4);
      float4 bv0 = *(const float4*)(Be2 + col), bv1 = *(const float4*)(Be2 + col + 4);
      LN1(a0[c].x, gv0.x, bv0.x); LN1(a0[c].y, gv0.y, bv0.y);
      LN1(a0[c].z, gv0.z, bv0.z); LN1(a0[c].w, gv0.w, bv0.w);
      LN1(a1[c].x, gv1.x, bv1.x); LN1(a1[c].y, gv1.y, bv1.y);
      LN1(a1[c].z, gv1.z, bv1.z); LN1(a1[c].w, gv1.w, bv1.w);
    }
  }

  f32x4 acc[4];
#pragma unroll
  for (int i = 0; i < 4; i++) acc[i] = {0.f, 0.f, 0.f, 0.f};
#pragma unroll
  for (int c = 0; c < 4; c++) {
    const float* wp = W1 + (size_t)(n0 + srow) * 128 + c * 32 + koff;
    float4 w0 = *(const float4*)wp, w1v = *(const float4*)(wp + 4);
    __syncthreads();
    *(short8*)&Asm[srow][koff] = cvt8(a0[c], a1[c]);
    *(short8*)&Wsm[srow][koff] = cvt8(w0, w1v);
    __syncthreads();
    short8 af = *(short8*)&Asm[wave * 16 + m16][quad * 8];
#pragma unroll
    for (int nt = 0; nt < 4; nt++) {
      short8 bf = *(short8*)&Wsm[nt * 16 + m16][quad * 8];
      acc[nt] = __builtin_amdgcn_mfma_f32_16x16x32_bf16(af, bf, acc[nt], 0, 0, 0);
    }
  }
#pragma unroll
  for (int nt = 0; nt < 4; nt++) {
#pragma unroll
    for (int r = 0; r < 4; r++) {
      const int m = m0 + wave * 16 + quad * 4 + r;
      const int n = n0 + nt * 16 + m16;
      float v = acc[nt][r] + B1[n];
      v = 0.5f * v * (1.0f + erff(v * 0.70710678118654752f));
      T1[(size_t)m * 512 + n] = v;
    }
  }
}

// ---------------- CSR scan + scatter ----------------
__global__ __launch_bounds__(256) void k_scan(const int* __restrict__ deg,
    int* __restrict__ offs, int* __restrict__ cursor) {
  __shared__ int sums[256];
  int t = threadIdx.x;
  int loc[16];
  int s = 0;
#pragma unroll
  for (int i = 0; i < 16; i++) { loc[i] = s; s += deg[t*16 + i]; }
  sums[t] = s;
  __syncthreads();
  for (int d = 1; d < 256; d <<= 1) {
    int v = (t >= d) ? sums[t - d] : 0;
    __syncthreads();
    sums[t] += v;
    __syncthreads();
  }
  int base = sums[t] - s;
#pragma unroll
  for (int i = 0; i < 16; i++) {
    offs[t*16 + i] = base + loc[i];
    cursor[t*16 + i] = base + loc[i];
  }
}
__global__ __launch_bounds__(256) void k_scatter(const int* __restrict__ EI,
    int* __restrict__ cursor, int* __restrict__ elist) {
  int is64 = detect64(EI);
  int e = blockIdx.x * 256 + threadIdx.x;
  int d = is64 ? EI[2*(NE+e)] : EI[NE+e];
  d = min(max(d, 0), NN-1);
  int slot = atomicAdd(&cursor[d], 1);
  elist[slot] = e;
}

// ---------------- per-dst aggregation (atomic-free; 4x unrolled gather) ----------------
__global__ __launch_bounds__(256) void k_edge_agg2(const int* __restrict__ EI,
    const int* __restrict__ deg, const int* __restrict__ offs,
    const int* __restrict__ elist, const unsigned short* __restrict__ Vl,
    const unsigned short* __restrict__ EB, float* __restrict__ AG) {
  int is64 = detect64(EI);
  int d = blockIdx.x * 4 + (threadIdx.x >> 6);
  int lane = threadIdx.x & 63;
  int degd = deg[d], start = offs[d];
  int hh = lane >> 3;
  float ss = 0.f;
  for (int i = lane & 7; i < degd; i += 8)
    ss += b2f16(EB[(size_t)elist[start + i] * 8 + hh]);
  for (int o = 1; o < 8; o <<= 1) ss += __shfl_xor(ss, o);
  float inv = 1.0f / fmaxf(ss, 1e-30f);
  float ax = 0.f, ay = 0.f;
  int i = 0;
  for (; i + 4 <= degd; i += 4) {
    int e0 = elist[start+i], e1 = elist[start+i+1], e2 = elist[start+i+2], e3 = elist[start+i+3];
    int s0 = is64 ? EI[2*e0] : EI[e0];
    int s1 = is64 ? EI[2*e1] : EI[e1];
    int s2 = is64 ? EI[2*e2] : EI[e2];
    int s3 = is64 ? EI[2*e3] : EI[e3];
    s0 = min(max(s0,0),NN-1); s1 = min(max(s1,0),NN-1);
    s2 = min(max(s2,0),NN-1); s3 = min(max(s3,0),NN-1);
    float w0 = b2f16(EB[(size_t)e0*8 + hh]) * inv;
    float w1 = b2f16(EB[(size_t)e1*8 + hh]) * inv;
    float w2 = b2f16(EB[(size_t)e2*8 + hh]) * inv;
    float w3 = b2f16(EB[(size_t)e3*8 + hh]) * inv;
    unsigned v0 = *(const unsigned*)(Vl + (size_t)s0 * DM + 2 * lane);
    unsigned v1 = *(const unsigned*)(Vl + (size_t)s1 * DM + 2 * lane);
    unsigned v2 = *(const unsigned*)(Vl + (size_t)s2 * DM + 2 * lane);
    unsigned v3 = *(const unsigned*)(Vl + (size_t)s3 * DM + 2 * lane);
    ax += w0 * b2f16((unsigned short)(v0 & 0xffffu)) + w1 * b2f16((unsigned short)(v1 & 0xffffu))
        + w2 * b2f16((unsigned short)(v2 & 0xffffu)) + w3 * b2f16((unsigned short)(v3 & 0xffffu));
    ay += w0 * b2f16((unsigned short)(v0 >> 16)) + w1 * b2f16((unsigned short)(v1 >> 16))
        + w2 * b2f16((unsigned short)(v2 >> 16)) + w3 * b2f16((unsigned short)(v3 >> 16));
  }
  for (; i < degd; i++) {
    int e = elist[start + i];
    int s = is64 ? EI[2*e] : EI[e];
    s = min(max(s, 0), NN-1);
    float a = b2f16(EB[(size_t)e*8 + hh]) * inv;
    unsigned v = *(const unsigned*)(Vl + (size_t)s * DM + 2 * lane);
    ax += a * b2f16((unsigned short)(v & 0xffffu));
    ay += a * b2f16((unsigned short)(v >> 16));
  }
  float2 r; r.x = ax; r.y = ay;
  *(float2*)(AG + (size_t)d * DM + 2 * lane) = r;
}

extern "C" void kernel_launch(void* const* d_in, const int* in_sizes, int n_in,
                              void* d_out, int out_size, void* d_ws, size_t ws_size,
                              hipStream_t stream) {
  const float* x     = (const float*)d_in[0];
  const int*   ei    = (const int*)  d_in[1];
  const float* wq_l  = (const float*)d_in[2];  const float* bq_l = (const float*)d_in[3];
  const float* wk_l  = (const float*)d_in[4];  const float* bk_l = (const float*)d_in[5];
  const float* wv_l  = (const float*)d_in[6];  const float* bv_l = (const float*)d_in[7];
  const float* wg    = (const float*)d_in[8];  const float* bg   = (const float*)d_in[9];
  const float* wq_g  = (const float*)d_in[10]; const float* bq_g = (const float*)d_in[11];
  const float* wk_g  = (const float*)d_in[12]; const float* bk_g = (const float*)d_in[13];
  const float* wv_g  = (const float*)d_in[14]; const float* bv_g = (const float*)d_in[15];
  const float* wo_g  = (const float*)d_in[16]; const float* bo_g = (const float*)d_in[17];
  const float* wf    = (const float*)d_in[18]; const float* bff  = (const float*)d_in[19];
  const float* gf    = (const float*)d_in[20]; const float* betaf= (const float*)d_in[21];
  const float* w1    = (const float*)d_in[22]; const float* b1   = (const float*)d_in[23];
  const float* w2    = (const float*)d_in[24]; const float* b2   = (const float*)d_in[25];
  const float* g1    = (const float*)d_in[26]; const float* be1  = (const float*)d_in[27];
  const float* g2    = (const float*)d_in[28]; const float* be2  = (const float*)d_in[29];
  float* out = (float*)d_out;

  const size_t NEED = (size_t)3289088 * 4;
  if (ws_size < NEED) {
    k_fill<<<2048, 256, 0, stream>>>(out, 100.0f, NN*DM);
    return;
  }

  float* W = (float*)d_ws;
  float*          lQ    = W + 0;
  float*          lK    = W + 524288;
  unsigned short* lV    = (unsigned short*)(W + 1048576);
  unsigned short* eb    = (unsigned short*)(W + 1310720);
  float*          go    = W + 1835008;
  unsigned short* qgb   = (unsigned short*)(W + 2359296);
  unsigned short* kgb   = (unsigned short*)(W + 2621440);   // head-major Kh[8][4096][16]
  unsigned short* vgT   = (unsigned short*)(W + 2883584);
  float*          agg   = W + 0;
  float*          local_= W + 524288;
  float*          gop   = W + 1048576;
  float*          tmpf  = W + 2097152;
  float*          h     = W + 2621440;
  float*          t1    = W + 0;
  int* deg    = (int*)(W + 3145728);
  int* cursor = (int*)(W + 3149824);
  int* offs   = (int*)(W + 3153920);
  int* elist  = (int*)(W + 3158016);

  dim3 b256(256);

  // gemm_six zeroes deg inline (block 0,0) — no memset dispatch
  gemm_six<<<dim3(64,12), b256, 0, stream>>>(x, g1, be1,
      wq_l, wk_l, wv_l, wq_g, wk_g, wv_g,
      bq_l, bk_l, bv_l, bq_g, bk_g, bv_g,
      lQ, lK, lV, qgb, kgb, vgT, deg);

  // fused global attention (32-row q-tiles, 2x parallelism) + edge scores
  k_attn_fused<<<3072, dim3(512), 0, stream>>>(kgb, qgb, vgT, go, ei, lQ, lK, eb, deg);

  k_scan<<<1, b256, 0, stream>>>(deg, offs, cursor);
  k_scatter<<<512, b256, 0, stream>>>(ei, cursor, elist);
  k_edge_agg2<<<1024, b256, 0, stream>>>(ei, deg, offs, elist, lV, eb, agg);

  gemm_dual<<<dim3(64,4), b256, 0, stream>>>(x, agg, go, wg, bg, wo_g, bo_g, local_, gop);

  gemm_mfma<<<dim3(64,2), b256, 0, stream>>>(local_,128, gop,128,128, wf, bff,
      nullptr,nullptr,nullptr, tmpf, 128, 256, 0, 0, 1.f);

  gemm_ffn1<<<dim3(64,8), b256, 0, stream>>>(tmpf, x, gf, betaf, g2, be2, w1, b1, h, t1);
  gemm_mfma<<<dim3(64,2), b256, 0, stream>>>(t1,512, nullptr,0,512, w2, b2,
      h, nullptr,nullptr, out, 128, 512, 0, 0, 1.f);
}

// Round 16
// 228.138 us; speedup vs baseline: 1.0558x; 1.0558x over previous
//
#include <hip/hip_runtime.h>
#include <math.h>

#define NN 4096
#define DM 128
#define NE 131072
#define QSCALE 0.36067376022224085f   // 0.25 * log2(e): exp(S/4) == exp2(S_prescaled)
#define ESCALE 0.36067376022224085f

typedef short short8 __attribute__((ext_vector_type(8)));
typedef float f32x4  __attribute__((ext_vector_type(4)));
typedef unsigned int uint4v __attribute__((ext_vector_type(4)));

// round-half-up pack of two fp32 -> bf16x2 via v_perm_b32
static __device__ __forceinline__ unsigned pk2(float lo, float hi) {
  union { float f; unsigned u; } a, b; a.f = lo; b.f = hi;
  return __builtin_amdgcn_perm(b.u + 0x8000u, a.u + 0x8000u, 0x07060302u);
}
// truncating pack via v_perm_b32 (1 op)
static __device__ __forceinline__ unsigned pkp(float lo, float hi) {
  union { float f; unsigned u; } a, b; a.f = lo; b.f = hi;
  return __builtin_amdgcn_perm(b.u, a.u, 0x07060302u);
}
static __device__ __forceinline__ unsigned short f2bh(float f) {
  union { float f; unsigned u; } v; v.f = f;
  return (unsigned short)((v.u + 0x8000u) >> 16);
}
static __device__ __forceinline__ float b2f16(unsigned short u) {
  union { unsigned u; float f; } v; v.u = ((unsigned)u) << 16; return v.f;
}
static __device__ __forceinline__ short8 cvt8(float4 a, float4 b) {
  uint4v u;
  u.x = pk2(a.x, a.y); u.y = pk2(a.z, a.w);
  u.z = pk2(b.x, b.y); u.w = pk2(b.z, b.w);
  return __builtin_bit_cast(short8, u);
}
static __device__ __forceinline__ int detect64(const int* __restrict__ EI) {
  int v = EI[2 * (threadIdx.x & 63) + 1];
  for (int off = 1; off < 64; off <<= 1) v |= __shfl_xor(v, off);
  return (v == 0) ? 1 : 0;
}

__global__ __launch_bounds__(256) void k_fill(float* __restrict__ out, float v, int n) {
  int i = blockIdx.x * 256 + threadIdx.x;
  if (i < n) out[i] = v;
}

// ---------------- MFMA GEMM: C = epi(A @ W^T + Bias) * oscale ----------------
__global__ __launch_bounds__(256) void gemm_mfma(
    const float* __restrict__ A0, int lda0,
    const float* __restrict__ A1, int lda1, int ksplit,
    const float* __restrict__ Wt, const float* __restrict__ Bias,
    const float* __restrict__ Res, const float* __restrict__ E0, const float* __restrict__ E1,
    void* __restrict__ Cp, int Nt, int K, int act, int omode, float oscale)
{
  __shared__ short Asm[64][40];
  __shared__ short Wsm[64][40];
  const int m0 = blockIdx.x * 64, n0 = blockIdx.y * 64;
  const int tid = threadIdx.x;
  const int srow = tid >> 2, koff = (tid & 3) * 8;
  const int lane = tid & 63, wave = tid >> 6;
  const int quad = lane >> 4, m16 = lane & 15;
  f32x4 acc[4];
#pragma unroll
  for (int i = 0; i < 4; i++) acc[i] = {0.f, 0.f, 0.f, 0.f};

  for (int k0 = 0; k0 < K; k0 += 32) {
    const int kg = k0 + koff;
    const float* ap = (kg < ksplit) ? (A0 + (size_t)(m0 + srow) * lda0 + kg)
                                    : (A1 + (size_t)(m0 + srow) * lda1 + (kg - ksplit));
    float4 a0 = *(const float4*)ap, a1 = *(const float4*)(ap + 4);
    const float* wp = Wt + (size_t)(n0 + srow) * K + kg;
    float4 w0 = *(const float4*)wp, w1v = *(const float4*)(wp + 4);
    __syncthreads();
    *(short8*)&Asm[srow][koff] = cvt8(a0, a1);
    *(short8*)&Wsm[srow][koff] = cvt8(w0, w1v);
    __syncthreads();
    short8 af = *(short8*)&Asm[wave * 16 + m16][quad * 8];
#pragma unroll
    for (int nt = 0; nt < 4; nt++) {
      short8 bf = *(short8*)&Wsm[nt * 16 + m16][quad * 8];
      acc[nt] = __builtin_amdgcn_mfma_f32_16x16x32_bf16(af, bf, acc[nt], 0, 0, 0);
    }
  }
#pragma unroll
  for (int nt = 0; nt < 4; nt++) {
#pragma unroll
    for (int r = 0; r < 4; r++) {
      const int m = m0 + wave * 16 + quad * 4 + r;
      const int n = n0 + nt * 16 + m16;
      float v = acc[nt][r] + Bias[n];
      size_t oi = (size_t)m * Nt + n;
      if (act == 1) v = 0.5f * v * (1.0f + erff(v * 0.70710678118654752f));
      else if (act == 2) {
        float g = 1.0f / (1.0f + __expf(fminf(fmaxf(-v, -80.f), 80.f)));
        v = g * E0[oi] + (1.0f - g) * E1[oi];
      }
      if (Res) v += Res[oi];
      v *= oscale;
      if (omode == 0)      ((float*)Cp)[oi] = v;
      else if (omode == 1) ((unsigned short*)Cp)[oi] = f2bh(v);
      else                 ((unsigned short*)Cp)[(size_t)n * NN + m] = f2bh(v);
    }
  }
}

// ---------------- six-way QKV GEMM with inline LN; block(0,0) zeroes deg ----------------
// omode: 0 fp32 [m][n]; 1 bf16 [m][n]; 2 bf16 [n][NN+m] (V^T); 3 bf16 head-major Kh[8][4096][16]
#define LN1(V, GV, BV) V = (V - mean) * rstd * GV + BV
__global__ __launch_bounds__(256) void gemm_six(
    const float* __restrict__ X,
    const float* __restrict__ G1, const float* __restrict__ Be1,
    const float* __restrict__ W0, const float* __restrict__ W1, const float* __restrict__ W2,
    const float* __restrict__ W3, const float* __restrict__ W4, const float* __restrict__ W5,
    const float* __restrict__ B0, const float* __restrict__ B1, const float* __restrict__ B2,
    const float* __restrict__ B3, const float* __restrict__ B4, const float* __restrict__ B5,
    void* __restrict__ O0, void* __restrict__ O1, void* __restrict__ O2,
    void* __restrict__ O3, void* __restrict__ O4, void* __restrict__ O5,
    int* __restrict__ deg)
{
  __shared__ short Asm[64][40];
  __shared__ short Wsm[64][40];
  if (blockIdx.x == 0 && blockIdx.y == 0) {
#pragma unroll
    for (int i = 0; i < 16; i++) deg[threadIdx.x * 16 + i] = 0;
  }
  const int g = blockIdx.y >> 1;
  const float* Wt  = (g==0)?W0:(g==1)?W1:(g==2)?W2:(g==3)?W3:(g==4)?W4:W5;
  const float* Bia = (g==0)?B0:(g==1)?B1:(g==2)?B2:(g==3)?B3:(g==4)?B4:B5;
  void* Cp         = (g==0)?O0:(g==1)?O1:(g==2)?O2:(g==3)?O3:(g==4)?O4:O5;
  const int omode  = (g==2)?1:(g==3)?1:(g==4)?3:(g==5)?2:0;
  const float osc  = (g==3)? QSCALE : (g==0)? ESCALE : 1.f;
  const int m0 = blockIdx.x * 64, n0 = (blockIdx.y & 1) * 64;
  const int tid = threadIdx.x;
  const int srow = tid >> 2, koff = (tid & 3) * 8;
  const int lane = tid & 63, wave = tid >> 6;
  const int quad = lane >> 4, m16 = lane & 15;

  const float* arow = X + (size_t)(m0 + srow) * 128 + koff;
  float4 a0[4], a1[4];
#pragma unroll
  for (int c = 0; c < 4; c++) {
    a0[c] = *(const float4*)(arow + c * 32);
    a1[c] = *(const float4*)(arow + c * 32 + 4);
  }
  if (g >= 3) {
    float s = 0.f;
#pragma unroll
    for (int c = 0; c < 4; c++)
      s += a0[c].x + a0[c].y + a0[c].z + a0[c].w + a1[c].x + a1[c].y + a1[c].z + a1[c].w;
    s += __shfl_xor(s, 1); s += __shfl_xor(s, 2);
    float mean = s * (1.0f / 128.0f);
    float v = 0.f;
#pragma unroll
    for (int c = 0; c < 4; c++) {
      float d;
      d = a0[c].x - mean; v += d*d;  d = a0[c].y - mean; v += d*d;
      d = a0[c].z - mean; v += d*d;  d = a0[c].w - mean; v += d*d;
      d = a1[c].x - mean; v += d*d;  d = a1[c].y - mean; v += d*d;
      d = a1[c].z - mean; v += d*d;  d = a1[c].w - mean; v += d*d;
    }
    v += __shfl_xor(v, 1); v += __shfl_xor(v, 2);
    float rstd = rsqrtf(v * (1.0f / 128.0f) + 1e-5f);
#pragma unroll
    for (int c = 0; c < 4; c++) {
      const int col = c * 32 + koff;
      float4 gv0 = *(const float4*)(G1 + col),  gv1 = *(const float4*)(G1 + col + 4);
      float4 bv0 = *(const float4*)(Be1 + col), bv1 = *(const float4*)(Be1 + col + 4);
      LN1(a0[c].x, gv0.x, bv0.x); LN1(a0[c].y, gv0.y, bv0.y);
      LN1(a0[c].z, gv0.z, bv0.z); LN1(a0[c].w, gv0.w, bv0.w);
      LN1(a1[c].x, gv1.x, bv1.x); LN1(a1[c].y, gv1.y, bv1.y);
      LN1(a1[c].z, gv1.z, bv1.z); LN1(a1[c].w, gv1.w, bv1.w);
    }
  }

  f32x4 acc[4];
#pragma unroll
  for (int i = 0; i < 4; i++) acc[i] = {0.f, 0.f, 0.f, 0.f};
#pragma unroll
  for (int c = 0; c < 4; c++) {
    const float* wp = Wt + (size_t)(n0 + srow) * 128 + c * 32 + koff;
    float4 w0 = *(const float4*)wp, w1v = *(const float4*)(wp + 4);
    __syncthreads();
    *(short8*)&Asm[srow][koff] = cvt8(a0[c], a1[c]);
    *(short8*)&Wsm[srow][koff] = cvt8(w0, w1v);
    __syncthreads();
    short8 af = *(short8*)&Asm[wave * 16 + m16][quad * 8];
#pragma unroll
    for (int nt = 0; nt < 4; nt++) {
      short8 bf = *(short8*)&Wsm[nt * 16 + m16][quad * 8];
      acc[nt] = __builtin_amdgcn_mfma_f32_16x16x32_bf16(af, bf, acc[nt], 0, 0, 0);
    }
  }
#pragma unroll
  for (int nt = 0; nt < 4; nt++) {
#pragma unroll
    for (int r = 0; r < 4; r++) {
      const int m = m0 + wave * 16 + quad * 4 + r;
      const int n = n0 + nt * 16 + m16;
      float v = (acc[nt][r] + Bia[n]) * osc;
      size_t oi = (size_t)m * 128 + n;
      if (omode == 0)      ((float*)Cp)[oi] = v;
      else if (omode == 1) ((unsigned short*)Cp)[oi] = f2bh(v);
      else if (omode == 3) ((unsigned short*)Cp)[(size_t)(n >> 4) * (NN * 16) + (size_t)m * 16 + (n & 15)] = f2bh(v);
      else                 ((unsigned short*)Cp)[(size_t)n * NN + m] = f2bh(v);
    }
  }
}

// ---------------- dual GEMM: y<2 = gate (K=256, act2), y>=2 = wo (K=128) ----------------
__global__ __launch_bounds__(256) void gemm_dual(
    const float* __restrict__ X, const float* __restrict__ AGG,
    const float* __restrict__ GO,
    const float* __restrict__ Wg, const float* __restrict__ Bg,
    const float* __restrict__ Wo, const float* __restrict__ Bo,
    float* __restrict__ LOCAL, float* __restrict__ GOP)
{
  __shared__ short Asm[64][40];
  __shared__ short Wsm[64][40];
  const int isGate = (blockIdx.y < 2);
  const float* A0  = isGate ? X   : GO;
  const float* A1  = isGate ? AGG : GO;
  const int ksplit = 128;
  const int K      = isGate ? 256 : 128;
  const float* Wt  = isGate ? Wg : Wo;
  const float* Bia = isGate ? Bg : Bo;
  float* Cp        = isGate ? LOCAL : GOP;
  const int m0 = blockIdx.x * 64, n0 = (blockIdx.y & 1) * 64;
  const int tid = threadIdx.x;
  const int srow = tid >> 2, koff = (tid & 3) * 8;
  const int lane = tid & 63, wave = tid >> 6;
  const int quad = lane >> 4, m16 = lane & 15;
  f32x4 acc[4];
#pragma unroll
  for (int i = 0; i < 4; i++) acc[i] = {0.f, 0.f, 0.f, 0.f};

  for (int k0 = 0; k0 < K; k0 += 32) {
    const int kg = k0 + koff;
    const float* ap = (kg < ksplit) ? (A0 + (size_t)(m0 + srow) * 128 + kg)
                                    : (A1 + (size_t)(m0 + srow) * 128 + (kg - ksplit));
    float4 a0 = *(const float4*)ap, a1 = *(const float4*)(ap + 4);
    const float* wp = Wt + (size_t)(n0 + srow) * K + kg;
    float4 w0 = *(const float4*)wp, w1v = *(const float4*)(wp + 4);
    __syncthreads();
    *(short8*)&Asm[srow][koff] = cvt8(a0, a1);
    *(short8*)&Wsm[srow][koff] = cvt8(w0, w1v);
    __syncthreads();
    short8 af = *(short8*)&Asm[wave * 16 + m16][quad * 8];
#pragma unroll
    for (int nt = 0; nt < 4; nt++) {
      short8 bf = *(short8*)&Wsm[nt * 16 + m16][quad * 8];
      acc[nt] = __builtin_amdgcn_mfma_f32_16x16x32_bf16(af, bf, acc[nt], 0, 0, 0);
    }
  }
#pragma unroll
  for (int nt = 0; nt < 4; nt++) {
#pragma unroll
    for (int r = 0; r < 4; r++) {
      const int m = m0 + wave * 16 + quad * 4 + r;
      const int n = n0 + nt * 16 + m16;
      float v = acc[nt][r] + Bia[n];
      size_t oi = (size_t)m * 128 + n;
      if (isGate) {
        float g = 1.0f / (1.0f + __expf(fminf(fmaxf(-v, -80.f), 80.f)));
        v = g * AGG[oi] + (1.0f - g) * X[oi];
      }
      Cp[oi] = v;
    }
  }
}

// ---------------- FUSED: global attention (blocks 0..511, 64 q-rows) + edge (512..2559) ----------------
// R13/R14-proven config: 64-row q-tiles, 8-way key split, head-major K.
__global__ __launch_bounds__(512) void k_attn_fused(
    const unsigned short* __restrict__ Kh, const unsigned short* __restrict__ Qb,
    const unsigned short* __restrict__ VT, float* __restrict__ O,
    const int* __restrict__ EI, const float* __restrict__ Q, const float* __restrict__ Kl,
    unsigned short* __restrict__ EB, int* __restrict__ deg)
{
  __shared__ float LO[8][4][16][16];
  __shared__ float LL[8][4][16];
  if (blockIdx.x >= 512) {
    // -------- edge attention part --------
    int is64 = detect64(EI);
    int gid = (blockIdx.x - 512) * 512 + threadIdx.x;
    int e = gid >> 3, hh = gid & 7;
    int s = is64 ? EI[2*e]      : EI[e];
    int d = is64 ? EI[2*(NE+e)] : EI[NE+e];
    s = min(max(s, 0), NN-1); d = min(max(d, 0), NN-1);
    const float4* qp = (const float4*)(Q  + (size_t)d * DM + hh * 16);
    const float4* kp = (const float4*)(Kl + (size_t)s * DM + hh * 16);
    float acc = 0.f;
#pragma unroll
    for (int c = 0; c < 4; c++) {
      float4 qa = qp[c], ka = kp[c];
      acc += qa.x*ka.x + qa.y*ka.y + qa.z*ka.z + qa.w*ka.w;
    }
    EB[(size_t)e*8 + hh] = f2bh(__builtin_amdgcn_exp2f(fminf(acc, 43.0f)));
    if (hh == 0) atomicAdd(&deg[d], 1);
    return;
  }
  // -------- global attention part --------
  const int h = blockIdx.x >> 6, qt = blockIdx.x & 63;
  const int tid = threadIdx.x, lane = tid & 63, wave = tid >> 6;   // wave 0..7
  const int quad = lane >> 4, m16 = lane & 15;
  const int r0 = qt * 64;
  const short8 z8 = {0,0,0,0,0,0,0,0};
  const f32x4  z4 = {0.f,0.f,0.f,0.f};
  short8 qf[4] = {z8, z8, z8, z8};
  if (quad < 2) {
#pragma unroll
    for (int j = 0; j < 4; j++)
      qf[j] = *(const short8*)(Qb + (size_t)(r0 + j * 16 + m16) * DM + h * 16 + quad * 8);
  }
  short8 ones;
#pragma unroll
  for (int i = 0; i < 8; i++) ones[i] = (short)0x3F80;
  const int kperm = (m16 >> 2) * 8 + (m16 & 3);
  const int kbase = wave * 512;
  const unsigned short* khead = Kh + (size_t)h * (NN * 16);
  f32x4 acc[4] = {z4, z4, z4, z4};
  f32x4 acc2[4] = {z4, z4, z4, z4};
  short8 a0 = z8, a1 = z8, a2 = z8, a3 = z8;
  for (int kt = 0; kt < 8; kt++) {
    const int key0 = kbase + kt * 64;
    if (quad < 2) {
      const unsigned short* kp = khead + (size_t)(key0 + kperm) * 16 + quad * 8;
      a0 = *(const short8*)kp;
      a1 = *(const short8*)(kp + 4 * 16);
      a2 = *(const short8*)(kp + 32 * 16);
      a3 = *(const short8*)(kp + 36 * 16);
    }
    const unsigned short* vp = VT + (size_t)(h * 16 + m16) * NN + key0 + quad * 8;
    short8 av0 = *(const short8*)vp;
    short8 av1 = *(const short8*)(vp + 32);
#pragma unroll
    for (int j = 0; j < 4; j++) {
      f32x4 s0 = __builtin_amdgcn_mfma_f32_16x16x32_bf16(a0, qf[j], z4, 0, 0, 0);
      f32x4 s1 = __builtin_amdgcn_mfma_f32_16x16x32_bf16(a1, qf[j], z4, 0, 0, 0);
      f32x4 s2 = __builtin_amdgcn_mfma_f32_16x16x32_bf16(a2, qf[j], z4, 0, 0, 0);
      f32x4 s3 = __builtin_amdgcn_mfma_f32_16x16x32_bf16(a3, qf[j], z4, 0, 0, 0);
      float e0 = __builtin_amdgcn_exp2f(s0[0]), e1 = __builtin_amdgcn_exp2f(s0[1]);
      float e2 = __builtin_amdgcn_exp2f(s0[2]), e3 = __builtin_amdgcn_exp2f(s0[3]);
      float e4 = __builtin_amdgcn_exp2f(s1[0]), e5 = __builtin_amdgcn_exp2f(s1[1]);
      float e6 = __builtin_amdgcn_exp2f(s1[2]), e7 = __builtin_amdgcn_exp2f(s1[3]);
      uint4v u;
      u.x = pkp(e0, e1); u.y = pkp(e2, e3); u.z = pkp(e4, e5); u.w = pkp(e6, e7);
      short8 p0 = __builtin_bit_cast(short8, u);
      float f0 = __builtin_amdgcn_exp2f(s2[0]), f1 = __builtin_amdgcn_exp2f(s2[1]);
      float f2 = __builtin_amdgcn_exp2f(s2[2]), f3 = __builtin_amdgcn_exp2f(s2[3]);
      float f4 = __builtin_amdgcn_exp2f(s3[0]), f5 = __builtin_amdgcn_exp2f(s3[1]);
      float f6 = __builtin_amdgcn_exp2f(s3[2]), f7 = __builtin_amdgcn_exp2f(s3[3]);
      uint4v w;
      w.x = pkp(f0, f1); w.y = pkp(f2, f3); w.z = pkp(f4, f5); w.w = pkp(f6, f7);
      short8 p1 = __builtin_bit_cast(short8, w);
      acc[j]  = __builtin_amdgcn_mfma_f32_16x16x32_bf16(av0, p0, acc[j], 0, 0, 0);
      acc[j]  = __builtin_amdgcn_mfma_f32_16x16x32_bf16(av1, p1, acc[j], 0, 0, 0);
      acc2[j] = __builtin_amdgcn_mfma_f32_16x16x32_bf16(ones, p0, acc2[j], 0, 0, 0);
      acc2[j] = __builtin_amdgcn_mfma_f32_16x16x32_bf16(ones, p1, acc2[j], 0, 0, 0);
    }
  }
#pragma unroll
  for (int j = 0; j < 4; j++) {
    float4 a4; a4.x = acc[j][0]; a4.y = acc[j][1]; a4.z = acc[j][2]; a4.w = acc[j][3];
    *(float4*)&LO[wave][j][m16][quad * 4] = a4;
    if (lane < 16) LL[wave][j][lane] = acc2[j][0];
  }
  __syncthreads();
  if (wave < 4) {
    const int j = wave;
    float4 o = *(float4*)&LO[0][j][m16][quad * 4];
    float lt = LL[0][j][m16];
#pragma unroll
    for (int w2 = 1; w2 < 8; w2++) {
      float4 t = *(float4*)&LO[w2][j][m16][quad * 4];
      o.x += t.x; o.y += t.y; o.z += t.z; o.w += t.w;
      lt += LL[w2][j][m16];
    }
    float inv = 1.0f / fmaxf(lt, 1e-30f);
    float4 r4; r4.x = o.x * inv; r4.y = o.y * inv; r4.z = o.z * inv; r4.w = o.w * inv;
    *(float4*)(O + (size_t)(r0 + j * 16 + m16) * DM + h * 16 + quad * 4) = r4;
  }
}

// ---------------- FFN first GEMM with inline h = x+relu(ln1(T)) and ln2 ----------------
__global__ __launch_bounds__(256) void gemm_ffn1(
    const float* __restrict__ T, const float* __restrict__ X,
    const float* __restrict__ Gf, const float* __restrict__ Bef,
    const float* __restrict__ G2, const float* __restrict__ Be2,
    const float* __restrict__ W1, const float* __restrict__ B1,
    float* __restrict__ H, float* __restrict__ T1)
{
  __shared__ short Asm[64][40];
  __shared__ short Wsm[64][40];
  const int m0 = blockIdx.x * 64, n0 = blockIdx.y * 64;
  const int tid = threadIdx.x;
  const int srow = tid >> 2, koff = (tid & 3) * 8;
  const int lane = tid & 63, wave = tid >> 6;
  const int quad = lane >> 4, m16 = lane & 15;

  const float* trow = T + (size_t)(m0 + srow) * 128 + koff;
  const float* xrow = X + (size_t)(m0 + srow) * 128 + koff;
  float4 a0[4], a1[4];
#pragma unroll
  for (int c = 0; c < 4; c++) {
    a0[c] = *(const float4*)(trow + c * 32);
    a1[c] = *(const float4*)(trow + c * 32 + 4);
  }
  {
    float s = 0.f;
#pragma unroll
    for (int c = 0; c < 4; c++)
      s += a0[c].x + a0[c].y + a0[c].z + a0[c].w + a1[c].x + a1[c].y + a1[c].z + a1[c].w;
    s += __shfl_xor(s, 1); s += __shfl_xor(s, 2);
    float mean = s * (1.0f / 128.0f);
    float v = 0.f;
#pragma unroll
    for (int c = 0; c < 4; c++) {
      float d;
      d = a0[c].x - mean; v += d*d;  d = a0[c].y - mean; v += d*d;
      d = a0[c].z - mean; v += d*d;  d = a0[c].w - mean; v += d*d;
      d = a1[c].x - mean; v += d*d;  d = a1[c].y - mean; v += d*d;
      d = a1[c].z - mean; v += d*d;  d = a1[c].w - mean; v += d*d;
    }
    v += __shfl_xor(v, 1); v += __shfl_xor(v, 2);
    float rstd = rsqrtf(v * (1.0f / 128.0f) + 1e-5f);
#pragma unroll
    for (int c = 0; c < 4; c++) {
      const int col = c * 32 + koff;
      float4 gv0 = *(const float4*)(Gf + col),  gv1 = *(const float4*)(Gf + col + 4);
      float4 bv0 = *(const float4*)(Bef + col), bv1 = *(const float4*)(Bef + col + 4);
      float4 x0 = *(const float4*)(xrow + c * 32), x1 = *(const float4*)(xrow + c * 32 + 4);
      LN1(a0[c].x, gv0.x, bv0.x); LN1(a0[c].y, gv0.y, bv0.y);
      LN1(a0[c].z, gv0.z, bv0.z); LN1(a0[c].w, gv0.w, bv0.w);
      LN1(a1[c].x, gv1.x, bv1.x); LN1(a1[c].y, gv1.y, bv1.y);
      LN1(a1[c].z, gv1.z, bv1.z); LN1(a1[c].w, gv1.w, bv1.w);
      a0[c].x = x0.x + fmaxf(a0[c].x, 0.f); a0[c].y = x0.y + fmaxf(a0[c].y, 0.f);
      a0[c].z = x0.z + fmaxf(a0[c].z, 0.f); a0[c].w = x0.w + fmaxf(a0[c].w, 0.f);
      a1[c].x = x1.x + fmaxf(a1[c].x, 0.f); a1[c].y = x1.y + fmaxf(a1[c].y, 0.f);
      a1[c].z = x1.z + fmaxf(a1[c].z, 0.f); a1[c].w = x1.w + fmaxf(a1[c].w, 0.f);
      if (blockIdx.y == 0) {
        *(float4*)(H + (size_t)(m0 + srow) * 128 + c * 32 + koff)     = a0[c];
        *(float4*)(H + (size_t)(m0 + srow) * 128 + c * 32 + koff + 4) = a1[c];
      }
    }
  }
  {
    float s = 0.f;
#pragma unroll
    for (int c = 0; c < 4; c++)
      s += a0[c].x + a0[c].y + a0[c].z + a0[c].w + a1[c].x + a1[c].y + a1[c].z + a1[c].w;
    s += __shfl_xor(s, 1); s += __shfl_xor(s, 2);
    float mean = s * (1.0f / 128.0f);
    float v = 0.f;
#pragma unroll
    for (int c = 0; c < 4; c++) {
      float d;
      d = a0[c].x - mean; v += d*d;  d = a0[c].y - mean; v += d*d;
      d = a0[c].z - mean; v += d*d;  d = a0[c].w - mean; v += d*d;
      d = a1[c].x - mean; v += d*d;  d = a1[c].y - mean; v += d*d;
      d = a1[c].z - mean; v += d*d;  d = a1[c].w - mean; v += d*d;
    }
    v += __shfl_xor(v, 1); v += __shfl_xor(v, 2);
    float rstd = rsqrtf(v * (1.0f / 128.0f) + 1e-5f);
#pragma unroll
    for (int c = 0; c < 4; c++) {
      const int col = c * 32 + koff;
      float4 gv0 = *(const float4*)(G2 + col),  gv1 = *(const float4*)(G2 + col + 4);
      float4 bv0 = *(const float4*)(Be2 + col), bv1 = *(const float4*)(Be2 + col + 4);
      LN1(a0[c].x, gv0.x, bv0.x); LN1(a0[c].y, gv0.y, bv0.y);
      LN1(a0[c].z, gv0.z, bv0.z); LN1(a0[c].w, gv0.w, bv0.w);
      LN1(a1[c].x, gv1.x, bv1.x); LN1(a1[c].y, gv1.y, bv1.y);
      LN1(a1[c].z, gv1.z, bv1.z); LN1(a1[c].w, gv1.w, bv1.w);
    }
  }

  f32x4 acc[4];
#pragma unroll
  for (int i = 0; i < 4; i++) acc[i] = {0.f, 0.f, 0.f, 0.f};
#pragma unroll
  for (int c = 0; c < 4; c++) {
    const float* wp = W1 + (size_t)(n0 + srow) * 128 + c * 32 + koff;
    float4 w0 = *(const float4*)wp, w1v = *(const float4*)(wp + 4);
    __syncthreads();
    *(short8*)&Asm[srow][koff] = cvt8(a0[c], a1[c]);
    *(short8*)&Wsm[srow][koff] = cvt8(w0, w1v);
    __syncthreads();
    short8 af = *(short8*)&Asm[wave * 16 + m16][quad * 8];
#pragma unroll
    for (int nt = 0; nt < 4; nt++) {
      short8 bf = *(short8*)&Wsm[nt * 16 + m16][quad * 8];
      acc[nt] = __builtin_amdgcn_mfma_f32_16x16x32_bf16(af, bf, acc[nt], 0, 0, 0);
    }
  }
#pragma unroll
  for (int nt = 0; nt < 4; nt++) {
#pragma unroll
    for (int r = 0; r < 4; r++) {
      const int m = m0 + wave * 16 + quad * 4 + r;
      const int n = n0 + nt * 16 + m16;
      float v = acc[nt][r] + B1[n];
      v = 0.5f * v * (1.0f + erff(v * 0.70710678118654752f));
      T1[(size_t)m * 512 + n] = v;
    }
  }
}

// ---------------- CSR scan + scatter ----------------
__global__ __launch_bounds__(256) void k_scan(const int* __restrict__ deg,
    int* __restrict__ offs, int* __restrict__ cursor) {
  __shared__ int sums[256];
  int t = threadIdx.x;
  int loc[16];
  int s = 0;
#pragma unroll
  for (int i = 0; i < 16; i++) { loc[i] = s; s += deg[t*16 + i]; }
  sums[t] = s;
  __syncthreads();
  for (int d = 1; d < 256; d <<= 1) {
    int v = (t >= d) ? sums[t - d] : 0;
    __syncthreads();
    sums[t] += v;
    __syncthreads();
  }
  int base = sums[t] - s;
#pragma unroll
  for (int i = 0; i < 16; i++) {
    offs[t*16 + i] = base + loc[i];
    cursor[t*16 + i] = base + loc[i];
  }
}
__global__ __launch_bounds__(256) void k_scatter(const int* __restrict__ EI,
    int* __restrict__ cursor, int* __restrict__ elist) {
  int is64 = detect64(EI);
  int e = blockIdx.x * 256 + threadIdx.x;
  int d = is64 ? EI[2*(NE+e)] : EI[NE+e];
  d = min(max(d, 0), NN-1);
  int slot = atomicAdd(&cursor[d], 1);
  elist[slot] = e;
}

// ---------------- per-dst aggregation: 2 waves per dst (halved serial gather chain) ----------------
__global__ __launch_bounds__(256) void k_edge_agg3(const int* __restrict__ EI,
    const int* __restrict__ deg, const int* __restrict__ offs,
    const int* __restrict__ elist, const unsigned short* __restrict__ Vl,
    const unsigned short* __restrict__ EB, float* __restrict__ AG) {
  __shared__ float PS[2][128];      // wave-1 partials per dst slot
  __shared__ float SSH[2][2][8];    // per-(dst,half) head sums
  int is64 = detect64(EI);
  int tid = threadIdx.x;
  int dsti = tid >> 7;              // 0..1 (two dst per block)
  int half = (tid >> 6) & 1;        // 0..1 (two waves per dst)
  int lane = tid & 63;
  int d = blockIdx.x * 2 + dsti;
  int degd = deg[d], start = offs[d];
  int hh = lane >> 3;
  float ss = 0.f;
  for (int i = (lane & 7) * 2 + half; i < degd; i += 16)
    ss += b2f16(EB[(size_t)elist[start + i] * 8 + hh]);
  for (int o = 1; o < 8; o <<= 1) ss += __shfl_xor(ss, o);
  if ((lane & 7) == 0) SSH[dsti][half][hh] = ss;
  __syncthreads();
  float inv = 1.0f / fmaxf(SSH[dsti][0][hh] + SSH[dsti][1][hh], 1e-30f);
  float ax = 0.f, ay = 0.f;
  int i = half;
  for (; i + 6 < degd; i += 8) {    // edges i, i+2, i+4, i+6 (this half's stride-2 set)
    int e0 = elist[start+i], e1 = elist[start+i+2], e2 = elist[start+i+4], e3 = elist[start+i+6];
    int s0 = is64 ? EI[2*e0] : EI[e0];
    int s1 = is64 ? EI[2*e1] : EI[e1];
    int s2 = is64 ? EI[2*e2] : EI[e2];
    int s3 = is64 ? EI[2*e3] : EI[e3];
    s0 = min(max(s0,0),NN-1); s1 = min(max(s1,0),NN-1);
    s2 = min(max(s2,0),NN-1); s3 = min(max(s3,0),NN-1);
    float w0 = b2f16(EB[(size_t)e0*8 + hh]) * inv;
    float w1 = b2f16(EB[(size_t)e1*8 + hh]) * inv;
    float w2 = b2f16(EB[(size_t)e2*8 + hh]) * inv;
    float w3 = b2f16(EB[(size_t)e3*8 + hh]) * inv;
    unsigned v0 = *(const unsigned*)(Vl + (size_t)s0 * DM + 2 * lane);
    unsigned v1 = *(const unsigned*)(Vl + (size_t)s1 * DM + 2 * lane);
    unsigned v2 = *(const unsigned*)(Vl + (size_t)s2 * DM + 2 * lane);
    unsigned v3 = *(const unsigned*)(Vl + (size_t)s3 * DM + 2 * lane);
    ax += w0 * b2f16((unsigned short)(v0 & 0xffffu)) + w1 * b2f16((unsigned short)(v1 & 0xffffu))
        + w2 * b2f16((unsigned short)(v2 & 0xffffu)) + w3 * b2f16((unsigned short)(v3 & 0xffffu));
    ay += w0 * b2f16((unsigned short)(v0 >> 16)) + w1 * b2f16((unsigned short)(v1 >> 16))
        + w2 * b2f16((unsigned short)(v2 >> 16)) + w3 * b2f16((unsigned short)(v3 >> 16));
  }
  for (; i < degd; i += 2) {
    int e = elist[start + i];
    int s = is64 ? EI[2*e] : EI[e];
    s = min(max(s, 0), NN-1);
    float a = b2f16(EB[(size_t)e*8 + hh]) * inv;
    unsigned v = *(const unsigned*)(Vl + (size_t)s * DM + 2 * lane);
    ax += a * b2f16((unsigned short)(v & 0xffffu));
    ay += a * b2f16((unsigned short)(v >> 16));
  }
  if (half == 1) { PS[dsti][2*lane] = ax; PS[dsti][2*lane+1] = ay; }
  __syncthreads();
  if (half == 0) {
    float2 r; r.x = ax + PS[dsti][2*lane]; r.y = ay + PS[dsti][2*lane+1];
    *(float2*)(AG + (size_t)d * DM + 2 * lane) = r;
  }
}

extern "C" void kernel_launch(void* const* d_in, const int* in_sizes, int n_in,
                              void* d_out, int out_size, void* d_ws, size_t ws_size,
                              hipStream_t stream) {
  const float* x     = (const float*)d_in[0];
  const int*   ei    = (const int*)  d_in[1];
  const float* wq_l  = (const float*)d_in[2];  const float* bq_l = (const float*)d_in[3];
  const float* wk_l  = (const float*)d_in[4];  const float* bk_l = (const float*)d_in[5];
  const float* wv_l  = (const float*)d_in[6];  const float* bv_l = (const float*)d_in[7];
  const float* wg    = (const float*)d_in[8];  const float* bg   = (const float*)d_in[9];
  const float* wq_g  = (const float*)d_in[10]; const float* bq_g = (const float*)d_in[11];
  const float* wk_g  = (const float*)d_in[12]; const float* bk_g = (const float*)d_in[13];
  const float* wv_g  = (const float*)d_in[14]; const float* bv_g = (const float*)d_in[15];
  const float* wo_g  = (const float*)d_in[16]; const float* bo_g = (const float*)d_in[17];
  const float* wf    = (const float*)d_in[18]; const float* bff  = (const float*)d_in[19];
  const float* gf    = (const float*)d_in[20]; const float* betaf= (const float*)d_in[21];
  const float* w1    = (const float*)d_in[22]; const float* b1   = (const float*)d_in[23];
  const float* w2    = (const float*)d_in[24]; const float* b2   = (const float*)d_in[25];
  const float* g1    = (const float*)d_in[26]; const float* be1  = (const float*)d_in[27];
  const float* g2    = (const float*)d_in[28]; const float* be2  = (const float*)d_in[29];
  float* out = (float*)d_out;

  const size_t NEED = (size_t)3289088 * 4;
  if (ws_size < NEED) {
    k_fill<<<2048, 256, 0, stream>>>(out, 100.0f, NN*DM);
    return;
  }

  float* W = (float*)d_ws;
  float*          lQ    = W + 0;
  float*          lK    = W + 524288;
  unsigned short* lV    = (unsigned short*)(W + 1048576);
  unsigned short* eb    = (unsigned short*)(W + 1310720);
  float*          go    = W + 1835008;
  unsigned short* qgb   = (unsigned short*)(W + 2359296);
  unsigned short* kgb   = (unsigned short*)(W + 2621440);   // head-major Kh[8][4096][16]
  unsigned short* vgT   = (unsigned short*)(W + 2883584);
  float*          agg   = W + 0;
  float*          local_= W + 524288;
  float*          gop   = W + 1048576;
  float*          tmpf  = W + 2097152;
  float*          h     = W + 2621440;
  float*          t1    = W + 0;
  int* deg    = (int*)(W + 3145728);
  int* cursor = (int*)(W + 3149824);
  int* offs   = (int*)(W + 3153920);
  int* elist  = (int*)(W + 3158016);

  dim3 b256(256);

  // gemm_six zeroes deg inline (block 0,0) — no memset dispatch
  gemm_six<<<dim3(64,12), b256, 0, stream>>>(x, g1, be1,
      wq_l, wk_l, wv_l, wq_g, wk_g, wv_g,
      bq_l, bk_l, bv_l, bq_g, bk_g, bv_g,
      lQ, lK, lV, qgb, kgb, vgT, deg);

  // fused global attention (64-row q-tiles, R13/R14-proven) + edge scores
  k_attn_fused<<<2560, dim3(512), 0, stream>>>(kgb, qgb, vgT, go, ei, lQ, lK, eb, deg);

  k_scan<<<1, b256, 0, stream>>>(deg, offs, cursor);
  k_scatter<<<512, b256, 0, stream>>>(ei, cursor, elist);
  k_edge_agg3<<<2048, b256, 0, stream>>>(ei, deg, offs, elist, lV, eb, agg);

  gemm_dual<<<dim3(64,4), b256, 0, stream>>>(x, agg, go, wg, bg, wo_g, bo_g, local_, gop);

  gemm_mfma<<<dim3(64,2), b256, 0, stream>>>(local_,128, gop,128,128, wf, bff,
      nullptr,nullptr,nullptr, tmpf, 128, 256, 0, 0, 1.f);

  gemm_ffn1<<<dim3(64,8), b256, 0, stream>>>(tmpf, x, gf, betaf, g2, be2, w1, b1, h, t1);
  gemm_mfma<<<dim3(64,2), b256, 0, stream>>>(t1,512, nullptr,0,512, w2, b2,
      h, nullptr,nullptr, out, 128, 512, 0, 0, 1.f);
}

// Round 17
// 221.581 us; speedup vs baseline: 1.0871x; 1.0296x over previous
//
#include <hip/hip_runtime.h>
#include <math.h>

#define NN 4096
#define DM 128
#define NE 131072
#define QSCALE 0.36067376022224085f   // 0.25 * log2(e): exp(S/4) == exp2(S_prescaled)
#define ESCALE 0.36067376022224085f

typedef short short8 __attribute__((ext_vector_type(8)));
typedef float f32x4  __attribute__((ext_vector_type(4)));
typedef unsigned int uint4v __attribute__((ext_vector_type(4)));

// round-half-up pack of two fp32 -> bf16x2 via v_perm_b32
static __device__ __forceinline__ unsigned pk2(float lo, float hi) {
  union { float f; unsigned u; } a, b; a.f = lo; b.f = hi;
  return __builtin_amdgcn_perm(b.u + 0x8000u, a.u + 0x8000u, 0x07060302u);
}
// truncating pack via v_perm_b32 (1 op)
static __device__ __forceinline__ unsigned pkp(float lo, float hi) {
  union { float f; unsigned u; } a, b; a.f = lo; b.f = hi;
  return __builtin_amdgcn_perm(b.u, a.u, 0x07060302u);
}
static __device__ __forceinline__ unsigned short f2bh(float f) {
  union { float f; unsigned u; } v; v.f = f;
  return (unsigned short)((v.u + 0x8000u) >> 16);
}
static __device__ __forceinline__ float b2f16(unsigned short u) {
  union { unsigned u; float f; } v; v.u = ((unsigned)u) << 16; return v.f;
}
static __device__ __forceinline__ short8 cvt8(float4 a, float4 b) {
  uint4v u;
  u.x = pk2(a.x, a.y); u.y = pk2(a.z, a.w);
  u.z = pk2(b.x, b.y); u.w = pk2(b.z, b.w);
  return __builtin_bit_cast(short8, u);
}
static __device__ __forceinline__ int detect64(const int* __restrict__ EI) {
  int v = EI[2 * (threadIdx.x & 63) + 1];
  for (int off = 1; off < 64; off <<= 1) v |= __shfl_xor(v, off);
  return (v == 0) ? 1 : 0;
}

__global__ __launch_bounds__(256) void k_fill(float* __restrict__ out, float v, int n) {
  int i = blockIdx.x * 256 + threadIdx.x;
  if (i < n) out[i] = v;
}

// ---------------- MFMA GEMM: C = epi(A @ W^T + Bias) * oscale ----------------
__global__ __launch_bounds__(256) void gemm_mfma(
    const float* __restrict__ A0, int lda0,
    const float* __restrict__ A1, int lda1, int ksplit,
    const float* __restrict__ Wt, const float* __restrict__ Bias,
    const float* __restrict__ Res, const float* __restrict__ E0, const float* __restrict__ E1,
    void* __restrict__ Cp, int Nt, int K, int act, int omode, float oscale)
{
  __shared__ short Asm[64][40];
  __shared__ short Wsm[64][40];
  const int m0 = blockIdx.x * 64, n0 = blockIdx.y * 64;
  const int tid = threadIdx.x;
  const int srow = tid >> 2, koff = (tid & 3) * 8;
  const int lane = tid & 63, wave = tid >> 6;
  const int quad = lane >> 4, m16 = lane & 15;
  f32x4 acc[4];
#pragma unroll
  for (int i = 0; i < 4; i++) acc[i] = {0.f, 0.f, 0.f, 0.f};

  for (int k0 = 0; k0 < K; k0 += 32) {
    const int kg = k0 + koff;
    const float* ap = (kg < ksplit) ? (A0 + (size_t)(m0 + srow) * lda0 + kg)
                                    : (A1 + (size_t)(m0 + srow) * lda1 + (kg - ksplit));
    float4 a0 = *(const float4*)ap, a1 = *(const float4*)(ap + 4);
    const float* wp = Wt + (size_t)(n0 + srow) * K + kg;
    float4 w0 = *(const float4*)wp, w1v = *(const float4*)(wp + 4);
    __syncthreads();
    *(short8*)&Asm[srow][koff] = cvt8(a0, a1);
    *(short8*)&Wsm[srow][koff] = cvt8(w0, w1v);
    __syncthreads();
    short8 af = *(short8*)&Asm[wave * 16 + m16][quad * 8];
#pragma unroll
    for (int nt = 0; nt < 4; nt++) {
      short8 bf = *(short8*)&Wsm[nt * 16 + m16][quad * 8];
      acc[nt] = __builtin_amdgcn_mfma_f32_16x16x32_bf16(af, bf, acc[nt], 0, 0, 0);
    }
  }
#pragma unroll
  for (int nt = 0; nt < 4; nt++) {
#pragma unroll
    for (int r = 0; r < 4; r++) {
      const int m = m0 + wave * 16 + quad * 4 + r;
      const int n = n0 + nt * 16 + m16;
      float v = acc[nt][r] + Bias[n];
      size_t oi = (size_t)m * Nt + n;
      if (act == 1) v = 0.5f * v * (1.0f + erff(v * 0.70710678118654752f));
      else if (act == 2) {
        float g = 1.0f / (1.0f + __expf(fminf(fmaxf(-v, -80.f), 80.f)));
        v = g * E0[oi] + (1.0f - g) * E1[oi];
      }
      if (Res) v += Res[oi];
      v *= oscale;
      if (omode == 0)      ((float*)Cp)[oi] = v;
      else if (omode == 1) ((unsigned short*)Cp)[oi] = f2bh(v);
      else                 ((unsigned short*)Cp)[(size_t)n * NN + m] = f2bh(v);
    }
  }
}

// ---------------- w2 GEMM with bf16 A (t1): out = t1 @ w2^T + b2 + h ----------------
__global__ __launch_bounds__(256) void gemm_w2b(
    const unsigned short* __restrict__ A,    // bf16 [4096][512]
    const float* __restrict__ Wt, const float* __restrict__ Bias,
    const float* __restrict__ Res, float* __restrict__ Cp)
{
  __shared__ short Asm[64][40];
  __shared__ short Wsm[64][40];
  const int m0 = blockIdx.x * 64, n0 = blockIdx.y * 64;
  const int tid = threadIdx.x;
  const int srow = tid >> 2, koff = (tid & 3) * 8;
  const int lane = tid & 63, wave = tid >> 6;
  const int quad = lane >> 4, m16 = lane & 15;
  f32x4 acc[4];
#pragma unroll
  for (int i = 0; i < 4; i++) acc[i] = {0.f, 0.f, 0.f, 0.f};

  for (int k0 = 0; k0 < 512; k0 += 32) {
    const int kg = k0 + koff;
    short8 av = *(const short8*)(A + (size_t)(m0 + srow) * 512 + kg);   // direct bf16 load
    const float* wp = Wt + (size_t)(n0 + srow) * 512 + kg;
    float4 w0 = *(const float4*)wp, w1v = *(const float4*)(wp + 4);
    __syncthreads();
    *(short8*)&Asm[srow][koff] = av;
    *(short8*)&Wsm[srow][koff] = cvt8(w0, w1v);
    __syncthreads();
    short8 af = *(short8*)&Asm[wave * 16 + m16][quad * 8];
#pragma unroll
    for (int nt = 0; nt < 4; nt++) {
      short8 bf = *(short8*)&Wsm[nt * 16 + m16][quad * 8];
      acc[nt] = __builtin_amdgcn_mfma_f32_16x16x32_bf16(af, bf, acc[nt], 0, 0, 0);
    }
  }
#pragma unroll
  for (int nt = 0; nt < 4; nt++) {
#pragma unroll
    for (int r = 0; r < 4; r++) {
      const int m = m0 + wave * 16 + quad * 4 + r;
      const int n = n0 + nt * 16 + m16;
      size_t oi = (size_t)m * 128 + n;
      Cp[oi] = acc[nt][r] + Bias[n] + Res[oi];
    }
  }
}

// ---------------- six-way QKV GEMM with inline LN; block(0,0) zeroes deg ----------------
// omode: 0 fp32 [m][n]; 1 bf16 [m][n]; 2 bf16 [n][NN+m] (V^T); 3 bf16 head-major Kh[8][4096][16]
#define LN1(V, GV, BV) V = (V - mean) * rstd * GV + BV
__global__ __launch_bounds__(256) void gemm_six(
    const float* __restrict__ X,
    const float* __restrict__ G1, const float* __restrict__ Be1,
    const float* __restrict__ W0, const float* __restrict__ W1, const float* __restrict__ W2,
    const float* __restrict__ W3, const float* __restrict__ W4, const float* __restrict__ W5,
    const float* __restrict__ B0, const float* __restrict__ B1, const float* __restrict__ B2,
    const float* __restrict__ B3, const float* __restrict__ B4, const float* __restrict__ B5,
    void* __restrict__ O0, void* __restrict__ O1, void* __restrict__ O2,
    void* __restrict__ O3, void* __restrict__ O4, void* __restrict__ O5,
    int* __restrict__ deg)
{
  __shared__ short Asm[64][40];
  __shared__ short Wsm[64][40];
  if (blockIdx.x == 0 && blockIdx.y == 0) {
#pragma unroll
    for (int i = 0; i < 16; i++) deg[threadIdx.x * 16 + i] = 0;
  }
  const int g = blockIdx.y >> 1;
  const float* Wt  = (g==0)?W0:(g==1)?W1:(g==2)?W2:(g==3)?W3:(g==4)?W4:W5;
  const float* Bia = (g==0)?B0:(g==1)?B1:(g==2)?B2:(g==3)?B3:(g==4)?B4:B5;
  void* Cp         = (g==0)?O0:(g==1)?O1:(g==2)?O2:(g==3)?O3:(g==4)?O4:O5;
  const int omode  = (g==2)?1:(g==3)?1:(g==4)?3:(g==5)?2:0;
  const float osc  = (g==3)? QSCALE : (g==0)? ESCALE : 1.f;
  const int m0 = blockIdx.x * 64, n0 = (blockIdx.y & 1) * 64;
  const int tid = threadIdx.x;
  const int srow = tid >> 2, koff = (tid & 3) * 8;
  const int lane = tid & 63, wave = tid >> 6;
  const int quad = lane >> 4, m16 = lane & 15;

  const float* arow = X + (size_t)(m0 + srow) * 128 + koff;
  float4 a0[4], a1[4];
#pragma unroll
  for (int c = 0; c < 4; c++) {
    a0[c] = *(const float4*)(arow + c * 32);
    a1[c] = *(const float4*)(arow + c * 32 + 4);
  }
  if (g >= 3) {
    float s = 0.f;
#pragma unroll
    for (int c = 0; c < 4; c++)
      s += a0[c].x + a0[c].y + a0[c].z + a0[c].w + a1[c].x + a1[c].y + a1[c].z + a1[c].w;
    s += __shfl_xor(s, 1); s += __shfl_xor(s, 2);
    float mean = s * (1.0f / 128.0f);
    float v = 0.f;
#pragma unroll
    for (int c = 0; c < 4; c++) {
      float d;
      d = a0[c].x - mean; v += d*d;  d = a0[c].y - mean; v += d*d;
      d = a0[c].z - mean; v += d*d;  d = a0[c].w - mean; v += d*d;
      d = a1[c].x - mean; v += d*d;  d = a1[c].y - mean; v += d*d;
      d = a1[c].z - mean; v += d*d;  d = a1[c].w - mean; v += d*d;
    }
    v += __shfl_xor(v, 1); v += __shfl_xor(v, 2);
    float rstd = rsqrtf(v * (1.0f / 128.0f) + 1e-5f);
#pragma unroll
    for (int c = 0; c < 4; c++) {
      const int col = c * 32 + koff;
      float4 gv0 = *(const float4*)(G1 + col),  gv1 = *(const float4*)(G1 + col + 4);
      float4 bv0 = *(const float4*)(Be1 + col), bv1 = *(const float4*)(Be1 + col + 4);
      LN1(a0[c].x, gv0.x, bv0.x); LN1(a0[c].y, gv0.y, bv0.y);
      LN1(a0[c].z, gv0.z, bv0.z); LN1(a0[c].w, gv0.w, bv0.w);
      LN1(a1[c].x, gv1.x, bv1.x); LN1(a1[c].y, gv1.y, bv1.y);
      LN1(a1[c].z, gv1.z, bv1.z); LN1(a1[c].w, gv1.w, bv1.w);
    }
  }

  f32x4 acc[4];
#pragma unroll
  for (int i = 0; i < 4; i++) acc[i] = {0.f, 0.f, 0.f, 0.f};
#pragma unroll
  for (int c = 0; c < 4; c++) {
    const float* wp = Wt + (size_t)(n0 + srow) * 128 + c * 32 + koff;
    float4 w0 = *(const float4*)wp, w1v = *(const float4*)(wp + 4);
    __syncthreads();
    *(short8*)&Asm[srow][koff] = cvt8(a0[c], a1[c]);
    *(short8*)&Wsm[srow][koff] = cvt8(w0, w1v);
    __syncthreads();
    short8 af = *(short8*)&Asm[wave * 16 + m16][quad * 8];
#pragma unroll
    for (int nt = 0; nt < 4; nt++) {
      short8 bf = *(short8*)&Wsm[nt * 16 + m16][quad * 8];
      acc[nt] = __builtin_amdgcn_mfma_f32_16x16x32_bf16(af, bf, acc[nt], 0, 0, 0);
    }
  }
#pragma unroll
  for (int nt = 0; nt < 4; nt++) {
#pragma unroll
    for (int r = 0; r < 4; r++) {
      const int m = m0 + wave * 16 + quad * 4 + r;
      const int n = n0 + nt * 16 + m16;
      float v = (acc[nt][r] + Bia[n]) * osc;
      size_t oi = (size_t)m * 128 + n;
      if (omode == 0)      ((float*)Cp)[oi] = v;
      else if (omode == 1) ((unsigned short*)Cp)[oi] = f2bh(v);
      else if (omode == 3) ((unsigned short*)Cp)[(size_t)(n >> 4) * (NN * 16) + (size_t)m * 16 + (n & 15)] = f2bh(v);
      else                 ((unsigned short*)Cp)[(size_t)n * NN + m] = f2bh(v);
    }
  }
}

// ---------------- dual GEMM: y<2 = gate (K=256, act2), y>=2 = wo (K=128) ----------------
__global__ __launch_bounds__(256) void gemm_dual(
    const float* __restrict__ X, const float* __restrict__ AGG,
    const float* __restrict__ GO,
    const float* __restrict__ Wg, const float* __restrict__ Bg,
    const float* __restrict__ Wo, const float* __restrict__ Bo,
    float* __restrict__ LOCAL, float* __restrict__ GOP)
{
  __shared__ short Asm[64][40];
  __shared__ short Wsm[64][40];
  const int isGate = (blockIdx.y < 2);
  const float* A0  = isGate ? X   : GO;
  const float* A1  = isGate ? AGG : GO;
  const int ksplit = 128;
  const int K      = isGate ? 256 : 128;
  const float* Wt  = isGate ? Wg : Wo;
  const float* Bia = isGate ? Bg : Bo;
  float* Cp        = isGate ? LOCAL : GOP;
  const int m0 = blockIdx.x * 64, n0 = (blockIdx.y & 1) * 64;
  const int tid = threadIdx.x;
  const int srow = tid >> 2, koff = (tid & 3) * 8;
  const int lane = tid & 63, wave = tid >> 6;
  const int quad = lane >> 4, m16 = lane & 15;
  f32x4 acc[4];
#pragma unroll
  for (int i = 0; i < 4; i++) acc[i] = {0.f, 0.f, 0.f, 0.f};

  for (int k0 = 0; k0 < K; k0 += 32) {
    const int kg = k0 + koff;
    const float* ap = (kg < ksplit) ? (A0 + (size_t)(m0 + srow) * 128 + kg)
                                    : (A1 + (size_t)(m0 + srow) * 128 + (kg - ksplit));
    float4 a0 = *(const float4*)ap, a1 = *(const float4*)(ap + 4);
    const float* wp = Wt + (size_t)(n0 + srow) * K + kg;
    float4 w0 = *(const float4*)wp, w1v = *(const float4*)(wp + 4);
    __syncthreads();
    *(short8*)&Asm[srow][koff] = cvt8(a0, a1);
    *(short8*)&Wsm[srow][koff] = cvt8(w0, w1v);
    __syncthreads();
    short8 af = *(short8*)&Asm[wave * 16 + m16][quad * 8];
#pragma unroll
    for (int nt = 0; nt < 4; nt++) {
      short8 bf = *(short8*)&Wsm[nt * 16 + m16][quad * 8];
      acc[nt] = __builtin_amdgcn_mfma_f32_16x16x32_bf16(af, bf, acc[nt], 0, 0, 0);
    }
  }
#pragma unroll
  for (int nt = 0; nt < 4; nt++) {
#pragma unroll
    for (int r = 0; r < 4; r++) {
      const int m = m0 + wave * 16 + quad * 4 + r;
      const int n = n0 + nt * 16 + m16;
      float v = acc[nt][r] + Bia[n];
      size_t oi = (size_t)m * 128 + n;
      if (isGate) {
        float g = 1.0f / (1.0f + __expf(fminf(fmaxf(-v, -80.f), 80.f)));
        v = g * AGG[oi] + (1.0f - g) * X[oi];
      }
      Cp[oi] = v;
    }
  }
}

// ---------------- FUSED: global attention (blocks 0..511, 64 q-rows) + edge (512..2559) ----------------
__global__ __launch_bounds__(512) void k_attn_fused(
    const unsigned short* __restrict__ Kh, const unsigned short* __restrict__ Qb,
    const unsigned short* __restrict__ VT, float* __restrict__ O,
    const int* __restrict__ EI, const float* __restrict__ Q, const float* __restrict__ Kl,
    unsigned short* __restrict__ EB, int* __restrict__ deg)
{
  __shared__ float LO[8][4][16][16];
  __shared__ float LL[8][4][16];
  if (blockIdx.x >= 512) {
    // -------- edge attention part --------
    int is64 = detect64(EI);
    int gid = (blockIdx.x - 512) * 512 + threadIdx.x;
    int e = gid >> 3, hh = gid & 7;
    int s = is64 ? EI[2*e]      : EI[e];
    int d = is64 ? EI[2*(NE+e)] : EI[NE+e];
    s = min(max(s, 0), NN-1); d = min(max(d, 0), NN-1);
    const float4* qp = (const float4*)(Q  + (size_t)d * DM + hh * 16);
    const float4* kp = (const float4*)(Kl + (size_t)s * DM + hh * 16);
    float acc = 0.f;
#pragma unroll
    for (int c = 0; c < 4; c++) {
      float4 qa = qp[c], ka = kp[c];
      acc += qa.x*ka.x + qa.y*ka.y + qa.z*ka.z + qa.w*ka.w;
    }
    EB[(size_t)e*8 + hh] = f2bh(__builtin_amdgcn_exp2f(fminf(acc, 43.0f)));
    if (hh == 0) atomicAdd(&deg[d], 1);
    return;
  }
  // -------- global attention part --------
  const int h = blockIdx.x >> 6, qt = blockIdx.x & 63;
  const int tid = threadIdx.x, lane = tid & 63, wave = tid >> 6;   // wave 0..7
  const int quad = lane >> 4, m16 = lane & 15;
  const int r0 = qt * 64;
  const short8 z8 = {0,0,0,0,0,0,0,0};
  const f32x4  z4 = {0.f,0.f,0.f,0.f};
  short8 qf[4] = {z8, z8, z8, z8};
  if (quad < 2) {
#pragma unroll
    for (int j = 0; j < 4; j++)
      qf[j] = *(const short8*)(Qb + (size_t)(r0 + j * 16 + m16) * DM + h * 16 + quad * 8);
  }
  short8 ones;
#pragma unroll
  for (int i = 0; i < 8; i++) ones[i] = (short)0x3F80;
  const int kperm = (m16 >> 2) * 8 + (m16 & 3);
  const int kbase = wave * 512;
  const unsigned short* khead = Kh + (size_t)h * (NN * 16);
  f32x4 acc[4] = {z4, z4, z4, z4};
  f32x4 acc2[4] = {z4, z4, z4, z4};
  short8 a0 = z8, a1 = z8, a2 = z8, a3 = z8;
  for (int kt = 0; kt < 8; kt++) {
    const int key0 = kbase + kt * 64;
    if (quad < 2) {
      const unsigned short* kp = khead + (size_t)(key0 + kperm) * 16 + quad * 8;
      a0 = *(const short8*)kp;
      a1 = *(const short8*)(kp + 4 * 16);
      a2 = *(const short8*)(kp + 32 * 16);
      a3 = *(const short8*)(kp + 36 * 16);
    }
    const unsigned short* vp = VT + (size_t)(h * 16 + m16) * NN + key0 + quad * 8;
    short8 av0 = *(const short8*)vp;
    short8 av1 = *(const short8*)(vp + 32);
#pragma unroll
    for (int j = 0; j < 4; j++) {
      f32x4 s0 = __builtin_amdgcn_mfma_f32_16x16x32_bf16(a0, qf[j], z4, 0, 0, 0);
      f32x4 s1 = __builtin_amdgcn_mfma_f32_16x16x32_bf16(a1, qf[j], z4, 0, 0, 0);
      f32x4 s2 = __builtin_amdgcn_mfma_f32_16x16x32_bf16(a2, qf[j], z4, 0, 0, 0);
      f32x4 s3 = __builtin_amdgcn_mfma_f32_16x16x32_bf16(a3, qf[j], z4, 0, 0, 0);
      float e0 = __builtin_amdgcn_exp2f(s0[0]), e1 = __builtin_amdgcn_exp2f(s0[1]);
      float e2 = __builtin_amdgcn_exp2f(s0[2]), e3 = __builtin_amdgcn_exp2f(s0[3]);
      float e4 = __builtin_amdgcn_exp2f(s1[0]), e5 = __builtin_amdgcn_exp2f(s1[1]);
      float e6 = __builtin_amdgcn_exp2f(s1[2]), e7 = __builtin_amdgcn_exp2f(s1[3]);
      uint4v u;
      u.x = pkp(e0, e1); u.y = pkp(e2, e3); u.z = pkp(e4, e5); u.w = pkp(e6, e7);
      short8 p0 = __builtin_bit_cast(short8, u);
      float f0 = __builtin_amdgcn_exp2f(s2[0]), f1 = __builtin_amdgcn_exp2f(s2[1]);
      float f2 = __builtin_amdgcn_exp2f(s2[2]), f3 = __builtin_amdgcn_exp2f(s2[3]);
      float f4 = __builtin_amdgcn_exp2f(s3[0]), f5 = __builtin_amdgcn_exp2f(s3[1]);
      float f6 = __builtin_amdgcn_exp2f(s3[2]), f7 = __builtin_amdgcn_exp2f(s3[3]);
      uint4v w;
      w.x = pkp(f0, f1); w.y = pkp(f2, f3); w.z = pkp(f4, f5); w.w = pkp(f6, f7);
      short8 p1 = __builtin_bit_cast(short8, w);
      acc[j]  = __builtin_amdgcn_mfma_f32_16x16x32_bf16(av0, p0, acc[j], 0, 0, 0);
      acc[j]  = __builtin_amdgcn_mfma_f32_16x16x32_bf16(av1, p1, acc[j], 0, 0, 0);
      acc2[j] = __builtin_amdgcn_mfma_f32_16x16x32_bf16(ones, p0, acc2[j], 0, 0, 0);
      acc2[j] = __builtin_amdgcn_mfma_f32_16x16x32_bf16(ones, p1, acc2[j], 0, 0, 0);
    }
  }
#pragma unroll
  for (int j = 0; j < 4; j++) {
    float4 a4; a4.x = acc[j][0]; a4.y = acc[j][1]; a4.z = acc[j][2]; a4.w = acc[j][3];
    *(float4*)&LO[wave][j][m16][quad * 4] = a4;
    if (lane < 16) LL[wave][j][lane] = acc2[j][0];
  }
  __syncthreads();
  if (wave < 4) {
    const int j = wave;
    float4 o = *(float4*)&LO[0][j][m16][quad * 4];
    float lt = LL[0][j][m16];
#pragma unroll
    for (int w2 = 1; w2 < 8; w2++) {
      float4 t = *(float4*)&LO[w2][j][m16][quad * 4];
      o.x += t.x; o.y += t.y; o.z += t.z; o.w += t.w;
      lt += LL[w2][j][m16];
    }
    float inv = 1.0f / fmaxf(lt, 1e-30f);
    float4 r4; r4.x = o.x * inv; r4.y = o.y * inv; r4.z = o.z * inv; r4.w = o.w * inv;
    *(float4*)(O + (size_t)(r0 + j * 16 + m16) * DM + h * 16 + quad * 4) = r4;
  }
}

// ---------------- FFN first GEMM with inline h = x+relu(ln1(T)) and ln2; t1 bf16 out ----------------
__global__ __launch_bounds__(256) void gemm_ffn1(
    const float* __restrict__ T, const float* __restrict__ X,
    const float* __restrict__ Gf, const float* __restrict__ Bef,
    const float* __restrict__ G2, const float* __restrict__ Be2,
    const float* __restrict__ W1, const float* __restrict__ B1,
    float* __restrict__ H, unsigned short* __restrict__ T1)
{
  __shared__ short Asm[64][40];
  __shared__ short Wsm[64][40];
  const int m0 = blockIdx.x * 64, n0 = blockIdx.y * 64;
  const int tid = threadIdx.x;
  const int srow = tid >> 2, koff = (tid & 3) * 8;
  const int lane = tid & 63, wave = tid >> 6;
  const int quad = lane >> 4, m16 = lane & 15;

  const float* trow = T + (size_t)(m0 + srow) * 128 + koff;
  const float* xrow = X + (size_t)(m0 + srow) * 128 + koff;
  float4 a0[4], a1[4];
#pragma unroll
  for (int c = 0; c < 4; c++) {
    a0[c] = *(const float4*)(trow + c * 32);
    a1[c] = *(const float4*)(trow + c * 32 + 4);
  }
  {
    float s = 0.f;
#pragma unroll
    for (int c = 0; c < 4; c++)
      s += a0[c].x + a0[c].y + a0[c].z + a0[c].w + a1[c].x + a1[c].y + a1[c].z + a1[c].w;
    s += __shfl_xor(s, 1); s += __shfl_xor(s, 2);
    float mean = s * (1.0f / 128.0f);
    float v = 0.f;
#pragma unroll
    for (int c = 0; c < 4; c++) {
      float d;
      d = a0[c].x - mean; v += d*d;  d = a0[c].y - mean; v += d*d;
      d = a0[c].z - mean; v += d*d;  d = a0[c].w - mean; v += d*d;
      d = a1[c].x - mean; v += d*d;  d = a1[c].y - mean; v += d*d;
      d = a1[c].z - mean; v += d*d;  d = a1[c].w - mean; v += d*d;
    }
    v += __shfl_xor(v, 1); v += __shfl_xor(v, 2);
    float rstd = rsqrtf(v * (1.0f / 128.0f) + 1e-5f);
#pragma unroll
    for (int c = 0; c < 4; c++) {
      const int col = c * 32 + koff;
      float4 gv0 = *(const float4*)(Gf + col),  gv1 = *(const float4*)(Gf + col + 4);
      float4 bv0 = *(const float4*)(Bef + col), bv1 = *(const float4*)(Bef + col + 4);
      float4 x0 = *(const float4*)(xrow + c * 32), x1 = *(const float4*)(xrow + c * 32 + 4);
      LN1(a0[c].x, gv0.x, bv0.x); LN1(a0[c].y, gv0.y, bv0.y);
      LN1(a0[c].z, gv0.z, bv0.z); LN1(a0[c].w, gv0.w, bv0.w);
      LN1(a1[c].x, gv1.x, bv1.x); LN1(a1[c].y, gv1.y, bv1.y);
      LN1(a1[c].z, gv1.z, bv1.z); LN1(a1[c].w, gv1.w, bv1.w);
      a0[c].x = x0.x + fmaxf(a0[c].x, 0.f); a0[c].y = x0.y + fmaxf(a0[c].y, 0.f);
      a0[c].z = x0.z + fmaxf(a0[c].z, 0.f); a0[c].w = x0.w + fmaxf(a0[c].w, 0.f);
      a1[c].x = x1.x + fmaxf(a1[c].x, 0.f); a1[c].y = x1.y + fmaxf(a1[c].y, 0.f);
      a1[c].z = x1.z + fmaxf(a1[c].z, 0.f); a1[c].w = x1.w + fmaxf(a1[c].w, 0.f);
      if (blockIdx.y == 0) {
        *(float4*)(H + (size_t)(m0 + srow) * 128 + c * 32 + koff)     = a0[c];
        *(float4*)(H + (size_t)(m0 + srow) * 128 + c * 32 + koff + 4) = a1[c];
      }
    }
  }
  {
    float s = 0.f;
#pragma unroll
    for (int c = 0; c < 4; c++)
      s += a0[c].x + a0[c].y + a0[c].z + a0[c].w + a1[c].x + a1[c].y + a1[c].z + a1[c].w;
    s += __shfl_xor(s, 1); s += __shfl_xor(s, 2);
    float mean = s * (1.0f / 128.0f);
    float v = 0.f;
#pragma unroll
    for (int c = 0; c < 4; c++) {
      float d;
      d = a0[c].x - mean; v += d*d;  d = a0[c].y - mean; v += d*d;
      d = a0[c].z - mean; v += d*d;  d = a0[c].w - mean; v += d*d;
      d = a1[c].x - mean; v += d*d;  d = a1[c].y - mean; v += d*d;
      d = a1[c].z - mean; v += d*d;  d = a1[c].w - mean; v += d*d;
    }
    v += __shfl_xor(v, 1); v += __shfl_xor(v, 2);
    float rstd = rsqrtf(v * (1.0f / 128.0f) + 1e-5f);
#pragma unroll
    for (int c = 0; c < 4; c++) {
      const int col = c * 32 + koff;
      float4 gv0 = *(const float4*)(G2 + col),  gv1 = *(const float4*)(G2 + col + 4);
      float4 bv0 = *(const float4*)(Be2 + col), bv1 = *(const float4*)(Be2 + col + 4);
      LN1(a0[c].x, gv0.x, bv0.x); LN1(a0[c].y, gv0.y, bv0.y);
      LN1(a0[c].z, gv0.z, bv0.z); LN1(a0[c].w, gv0.w, bv0.w);
      LN1(a1[c].x, gv1.x, bv1.x); LN1(a1[c].y, gv1.y, bv1.y);
      LN1(a1[c].z, gv1.z, bv1.z); LN1(a1[c].w, gv1.w, bv1.w);
    }
  }

  f32x4 acc[4];
#pragma unroll
  for (int i = 0; i < 4; i++) acc[i] = {0.f, 0.f, 0.f, 0.f};
#pragma unroll
  for (int c = 0; c < 4; c++) {
    const float* wp = W1 + (size_t)(n0 + srow) * 128 + c * 32 + koff;
    float4 w0 = *(const float4*)wp, w1v = *(const float4*)(wp + 4);
    __syncthreads();
    *(short8*)&Asm[srow][koff] = cvt8(a0[c], a1[c]);
    *(short8*)&Wsm[srow][koff] = cvt8(w0, w1v);
    __syncthreads();
    short8 af = *(short8*)&Asm[wave * 16 + m16][quad * 8];
#pragma unroll
    for (int nt = 0; nt < 4; nt++) {
      short8 bf = *(short8*)&Wsm[nt * 16 + m16][quad * 8];
      acc[nt] = __builtin_amdgcn_mfma_f32_16x16x32_bf16(af, bf, acc[nt], 0, 0, 0);
    }
  }
#pragma unroll
  for (int nt = 0; nt < 4; nt++) {
#pragma unroll
    for (int r = 0; r < 4; r++) {
      const int m = m0 + wave * 16 + quad * 4 + r;
      const int n = n0 + nt * 16 + m16;
      float v = acc[nt][r] + B1[n];
      v = 0.5f * v * (1.0f + erff(v * 0.70710678118654752f));
      T1[(size_t)m * 512 + n] = f2bh(v);
    }
  }
}

// ---------------- CSR scan + scatter ----------------
__global__ __launch_bounds__(256) void k_scan(const int* __restrict__ deg,
    int* __restrict__ offs, int* __restrict__ cursor) {
  __shared__ int sums[256];
  int t = threadIdx.x;
  int loc[16];
  int s = 0;
#pragma unroll
  for (int i = 0; i < 16; i++) { loc[i] = s; s += deg[t*16 + i]; }
  sums[t] = s;
  __syncthreads();
  for (int d = 1; d < 256; d <<= 1) {
    int v = (t >= d) ? sums[t - d] : 0;
    __syncthreads();
    sums[t] += v;
    __syncthreads();
  }
  int base = sums[t] - s;
#pragma unroll
  for (int i = 0; i < 16; i++) {
    offs[t*16 + i] = base + loc[i];
    cursor[t*16 + i] = base + loc[i];
  }
}
__global__ __launch_bounds__(256) void k_scatter(const int* __restrict__ EI,
    int* __restrict__ cursor, int* __restrict__ elist) {
  int is64 = detect64(EI);
  int e = blockIdx.x * 256 + threadIdx.x;
  int d = is64 ? EI[2*(NE+e)] : EI[NE+e];
  d = min(max(d, 0), NN-1);
  int slot = atomicAdd(&cursor[d], 1);
  elist[slot] = e;
}

// ---------------- per-dst aggregation: 2 waves per dst ----------------
__global__ __launch_bounds__(256) void k_edge_agg3(const int* __restrict__ EI,
    const int* __restrict__ deg, const int* __restrict__ offs,
    const int* __restrict__ elist, const unsigned short* __restrict__ Vl,
    const unsigned short* __restrict__ EB, float* __restrict__ AG) {
  __shared__ float PS[2][128];
  __shared__ float SSH[2][2][8];
  int is64 = detect64(EI);
  int tid = threadIdx.x;
  int dsti = tid >> 7;
  int half = (tid >> 6) & 1;
  int lane = tid & 63;
  int d = blockIdx.x * 2 + dsti;
  int degd = deg[d], start = offs[d];
  int hh = lane >> 3;
  float ss = 0.f;
  for (int i = (lane & 7) * 2 + half; i < degd; i += 16)
    ss += b2f16(EB[(size_t)elist[start + i] * 8 + hh]);
  for (int o = 1; o < 8; o <<= 1) ss += __shfl_xor(ss, o);
  if ((lane & 7) == 0) SSH[dsti][half][hh] = ss;
  __syncthreads();
  float inv = 1.0f / fmaxf(SSH[dsti][0][hh] + SSH[dsti][1][hh], 1e-30f);
  float ax = 0.f, ay = 0.f;
  int i = half;
  for (; i + 6 < degd; i += 8) {
    int e0 = elist[start+i], e1 = elist[start+i+2], e2 = elist[start+i+4], e3 = elist[start+i+6];
    int s0 = is64 ? EI[2*e0] : EI[e0];
    int s1 = is64 ? EI[2*e1] : EI[e1];
    int s2 = is64 ? EI[2*e2] : EI[e2];
    int s3 = is64 ? EI[2*e3] : EI[e3];
    s0 = min(max(s0,0),NN-1); s1 = min(max(s1,0),NN-1);
    s2 = min(max(s2,0),NN-1); s3 = min(max(s3,0),NN-1);
    float w0 = b2f16(EB[(size_t)e0*8 + hh]) * inv;
    float w1 = b2f16(EB[(size_t)e1*8 + hh]) * inv;
    float w2 = b2f16(EB[(size_t)e2*8 + hh]) * inv;
    float w3 = b2f16(EB[(size_t)e3*8 + hh]) * inv;
    unsigned v0 = *(const unsigned*)(Vl + (size_t)s0 * DM + 2 * lane);
    unsigned v1 = *(const unsigned*)(Vl + (size_t)s1 * DM + 2 * lane);
    unsigned v2 = *(const unsigned*)(Vl + (size_t)s2 * DM + 2 * lane);
    unsigned v3 = *(const unsigned*)(Vl + (size_t)s3 * DM + 2 * lane);
    ax += w0 * b2f16((unsigned short)(v0 & 0xffffu)) + w1 * b2f16((unsigned short)(v1 & 0xffffu))
        + w2 * b2f16((unsigned short)(v2 & 0xffffu)) + w3 * b2f16((unsigned short)(v3 & 0xffffu));
    ay += w0 * b2f16((unsigned short)(v0 >> 16)) + w1 * b2f16((unsigned short)(v1 >> 16))
        + w2 * b2f16((unsigned short)(v2 >> 16)) + w3 * b2f16((unsigned short)(v3 >> 16));
  }
  for (; i < degd; i += 2) {
    int e = elist[start + i];
    int s = is64 ? EI[2*e] : EI[e];
    s = min(max(s, 0), NN-1);
    float a = b2f16(EB[(size_t)e*8 + hh]) * inv;
    unsigned v = *(const unsigned*)(Vl + (size_t)s * DM + 2 * lane);
    ax += a * b2f16((unsigned short)(v & 0xffffu));
    ay += a * b2f16((unsigned short)(v >> 16));
  }
  if (half == 1) { PS[dsti][2*lane] = ax; PS[dsti][2*lane+1] = ay; }
  __syncthreads();
  if (half == 0) {
    float2 r; r.x = ax + PS[dsti][2*lane]; r.y = ay + PS[dsti][2*lane+1];
    *(float2*)(AG + (size_t)d * DM + 2 * lane) = r;
  }
}

extern "C" void kernel_launch(void* const* d_in, const int* in_sizes, int n_in,
                              void* d_out, int out_size, void* d_ws, size_t ws_size,
                              hipStream_t stream) {
  const float* x     = (const float*)d_in[0];
  const int*   ei    = (const int*)  d_in[1];
  const float* wq_l  = (const float*)d_in[2];  const float* bq_l = (const float*)d_in[3];
  const float* wk_l  = (const float*)d_in[4];  const float* bk_l = (const float*)d_in[5];
  const float* wv_l  = (const float*)d_in[6];  const float* bv_l = (const float*)d_in[7];
  const float* wg    = (const float*)d_in[8];  const float* bg   = (const float*)d_in[9];
  const float* wq_g  = (const float*)d_in[10]; const float* bq_g = (const float*)d_in[11];
  const float* wk_g  = (const float*)d_in[12]; const float* bk_g = (const float*)d_in[13];
  const float* wv_g  = (const float*)d_in[14]; const float* bv_g = (const float*)d_in[15];
  const float* wo_g  = (const float*)d_in[16]; const float* bo_g = (const float*)d_in[17];
  const float* wf    = (const float*)d_in[18]; const float* bff  = (const float*)d_in[19];
  const float* gf    = (const float*)d_in[20]; const float* betaf= (const float*)d_in[21];
  const float* w1    = (const float*)d_in[22]; const float* b1   = (const float*)d_in[23];
  const float* w2    = (const float*)d_in[24]; const float* b2   = (const float*)d_in[25];
  const float* g1    = (const float*)d_in[26]; const float* be1  = (const float*)d_in[27];
  const float* g2    = (const float*)d_in[28]; const float* be2  = (const float*)d_in[29];
  float* out = (float*)d_out;

  const size_t NEED = (size_t)3289088 * 4;
  if (ws_size < NEED) {
    k_fill<<<2048, 256, 0, stream>>>(out, 100.0f, NN*DM);
    return;
  }

  // workspace (float offsets). t1 now bf16 at [0,1048576 floats): spans agg/local_ slots,
  // both dead when ffn1 runs. All other slots unchanged from R16-proven layout.
  float* W = (float*)d_ws;
  float*          lQ    = W + 0;
  float*          lK    = W + 524288;
  unsigned short* lV    = (unsigned short*)(W + 1048576);
  unsigned short* eb    = (unsigned short*)(W + 1310720);
  float*          go    = W + 1835008;
  unsigned short* qgb   = (unsigned short*)(W + 2359296);
  unsigned short* kgb   = (unsigned short*)(W + 2621440);   // head-major Kh[8][4096][16]
  unsigned short* vgT   = (unsigned short*)(W + 2883584);
  float*          agg   = W + 0;
  float*          local_= W + 524288;
  float*          gop   = W + 1048576;
  float*          tmpf  = W + 2097152;
  float*          h     = W + 2621440;
  unsigned short* t1    = (unsigned short*)(W + 0);         // bf16 4096x512
  int* deg    = (int*)(W + 3145728);
  int* cursor = (int*)(W + 3149824);
  int* offs   = (int*)(W + 3153920);
  int* elist  = (int*)(W + 3158016);

  dim3 b256(256);

  // gemm_six zeroes deg inline (block 0,0) — no memset dispatch
  gemm_six<<<dim3(64,12), b256, 0, stream>>>(x, g1, be1,
      wq_l, wk_l, wv_l, wq_g, wk_g, wv_g,
      bq_l, bk_l, bv_l, bq_g, bk_g, bv_g,
      lQ, lK, lV, qgb, kgb, vgT, deg);

  // fused global attention (64-row q-tiles, R13/R14-proven) + edge scores
  k_attn_fused<<<2560, dim3(512), 0, stream>>>(kgb, qgb, vgT, go, ei, lQ, lK, eb, deg);

  k_scan<<<1, b256, 0, stream>>>(deg, offs, cursor);
  k_scatter<<<512, b256, 0, stream>>>(ei, cursor, elist);
  k_edge_agg3<<<2048, b256, 0, stream>>>(ei, deg, offs, elist, lV, eb, agg);

  gemm_dual<<<dim3(64,4), b256, 0, stream>>>(x, agg, go, wg, bg, wo_g, bo_g, local_, gop);

  gemm_mfma<<<dim3(64,2), b256, 0, stream>>>(local_,128, gop,128,128, wf, bff,
      nullptr,nullptr,nullptr, tmpf, 128, 256, 0, 0, 1.f);

  gemm_ffn1<<<dim3(64,8), b256, 0, stream>>>(tmpf, x, gf, betaf, g2, be2, w1, b1, h, t1);
  gemm_w2b<<<dim3(64,2), b256, 0, stream>>>(t1, w2, b2, h, out);
}